// Round 6
// baseline (2959.526 us; speedup 1.0000x reference)
//
#include <hip/hip_runtime.h>

#define BB 8
#define HH 48
#define WW 48
#define DD 64
#define NSEQ (HH*WW)   // 2304

typedef unsigned short u16;
typedef __attribute__((ext_vector_type(8))) short short8;
typedef __attribute__((ext_vector_type(4))) float f32x4;

__device__ __forceinline__ float bf2f(u16 u){ return __uint_as_float(((unsigned)u)<<16); }
__device__ __forceinline__ u16 f2bf(float f){
  unsigned u = __float_as_uint(f);
  return (u16)((u + 0x7fffu + ((u>>16)&1u)) >> 16);   // RNE
}

// ---------------- conv 64->64, NC weight sets; f32 input/weights, bf16 outputs ----------
struct ConvPtrsF {
  const float* W[3];
  const float* bias[3];
  u16* out[3];
};

template<int NC>
__global__ __launch_bounds__(256) void conv64_f(const float* __restrict__ in, ConvPtrsF p){
  __shared__ float lds[3][WW+2][64];
  const int b = blockIdx.x / HH, y = blockIdx.x % HH;
  const int tid = threadIdx.x, lane = tid & 63, wave = tid >> 6;
  const f32x4 z4 = {0.f,0.f,0.f,0.f};

  for(int ky=0; ky<3; ky++){
    int ys = y + ky - 1;
    if(ys < 0 || ys >= HH){
      for(int c = tid; c < WW*64/4; c += 256){
        int px = c >> 4, cb = (c & 15)*4;
        *(f32x4*)&lds[ky][px+1][cb] = z4;
      }
    } else {
      const float* rp = in + (size_t)(b*HH + ys)*WW*64;
      for(int c = tid; c < WW*64/4; c += 256){
        int px = c >> 4, cb = (c & 15)*4;
        *(f32x4*)&lds[ky][px+1][cb] = *(const f32x4*)&rp[px*64 + cb];
      }
    }
    for(int c = tid; c < 32; c += 256){
      int which = c >> 4, cb = (c & 15)*4;
      *(f32x4*)&lds[ky][which ? (WW+1) : 0][cb] = z4;
    }
  }
  __syncthreads();

  float acc[12][NC];
  #pragma unroll
  for(int i=0;i<12;i++)
    #pragma unroll
    for(int c=0;c<NC;c++) acc[i][c] = 0.f;

  const int px0 = wave*12;
  for(int ky=0; ky<3; ky++)
  for(int kx=0; kx<3; kx++){
    const int kk = ky*3 + kx;
    for(int c4=0; c4<16; c4++){
      f32x4 a[12];
      #pragma unroll
      for(int i=0;i<12;i++) a[i] = *(const f32x4*)&lds[ky][px0+i+kx][c4*4];
      #pragma unroll
      for(int c=0;c<NC;c++){
        #pragma unroll
        for(int q=0;q<4;q++){
          float w = p.W[c][(size_t)(kk*64 + c4*4 + q)*64 + lane];
          #pragma unroll
          for(int i=0;i<12;i++) acc[i][c] += a[i][q]*w;
        }
      }
    }
  }

  #pragma unroll
  for(int c=0;c<NC;c++){
    float bs = p.bias[c][lane];
    u16* op = p.out[c] + ((size_t)(b*HH + y)*WW)*64 + lane;
    #pragma unroll
    for(int i=0;i<12;i++)
      op[(size_t)(px0+i)*64] = f2bf(acc[i][c] + bs);
  }
}

// ---------------- flash attention, pure VALU: 4 threads per q row; bf16 in/out ----------
__global__ __launch_bounds__(256) void attn_valu(
    const u16* __restrict__ q, const u16* __restrict__ k, const u16* __restrict__ v,
    u16* __restrict__ z){
  __shared__ float Ks[64][68];
  __shared__ float Vs[64][68];
  const int qt = blockIdx.x, b = blockIdx.y;
  const int tid = threadIdx.x, sub = tid & 3, qi = tid >> 2;   // qi in [0,64)

  float qr[64];
  const u16* qp = q + ((size_t)(b*NSEQ + qt*64 + qi))*DD;
  #pragma unroll
  for(int c8=0;c8<8;c8++){
    short8 vv = *(const short8*)&qp[c8*8];
    #pragma unroll
    for(int j=0;j<8;j++) qr[c8*8+j] = bf2f((u16)vv[j]);
  }

  float o[64];
  #pragma unroll
  for(int d=0;d<64;d++) o[d] = 0.f;
  float mm = -1e30f, ll = 0.f;

  for(int kt=0; kt<NSEQ/64; kt++){
    __syncthreads();
    const u16* kp = k + ((size_t)(b*NSEQ + kt*64))*DD;
    const u16* vp = v + ((size_t)(b*NSEQ + kt*64))*DD;
    for(int c8=tid; c8<512; c8+=256){
      int r = c8>>3, cb = (c8&7)*8;
      short8 kv = *(const short8*)&kp[r*DD + cb];
      short8 vv = *(const short8*)&vp[r*DD + cb];
      #pragma unroll
      for(int j=0;j<8;j++){
        Ks[r][cb+j] = bf2f((u16)kv[j]);
        Vs[r][cb+j] = bf2f((u16)vv[j]);
      }
    }
    __syncthreads();

    float s[16];
    #pragma unroll
    for(int kk=0;kk<16;kk++){
      const float* krow = &Ks[sub*16 + kk][0];
      float acc = 0.f;
      #pragma unroll
      for(int d4=0; d4<16; d4++){
        f32x4 k4 = *(const f32x4*)(krow + d4*4);
        acc += qr[d4*4+0]*k4[0] + qr[d4*4+1]*k4[1]
             + qr[d4*4+2]*k4[2] + qr[d4*4+3]*k4[3];
      }
      s[kk] = acc;
    }

    float tm = s[0];
    #pragma unroll
    for(int kk=1;kk<16;kk++) tm = fmaxf(tm, s[kk]);
    tm = fmaxf(tm, __shfl_xor(tm, 1));
    tm = fmaxf(tm, __shfl_xor(tm, 2));
    float mnew = fmaxf(mm, tm);
    float sc = __expf(mm - mnew);
    ll *= sc;
    #pragma unroll
    for(int d=0;d<64;d++) o[d] *= sc;
    float pk[16];
    float rs = 0.f;
    #pragma unroll
    for(int kk=0;kk<16;kk++){ pk[kk] = __expf(s[kk] - mnew); rs += pk[kk]; }
    rs += __shfl_xor(rs, 1);
    rs += __shfl_xor(rs, 2);
    ll += rs;
    mm = mnew;

    #pragma unroll
    for(int kk=0;kk<16;kk++){
      float pv = pk[kk];
      const float* vrow = &Vs[sub*16 + kk][0];
      #pragma unroll
      for(int d4=0; d4<16; d4++){
        f32x4 v4 = *(const f32x4*)(vrow + d4*4);
        o[d4*4+0] += pv*v4[0];
        o[d4*4+1] += pv*v4[1];
        o[d4*4+2] += pv*v4[2];
        o[d4*4+3] += pv*v4[3];
      }
    }
  }

  #pragma unroll
  for(int d=0;d<64;d++){
    o[d] += __shfl_xor(o[d], 1);
    o[d] += __shfl_xor(o[d], 2);
  }
  if(sub == 0){
    float inv = 1.f/ll;
    u16* zp = z + ((size_t)(b*NSEQ + qt*64 + qi))*DD;
    #pragma unroll
    for(int d=0;d<64;d++) zp[d] = f2bf(o[d]*inv);
  }
}

// -------- big conv (concat input): in0 bf16, in1 bf16 or f32; f32 weights;
// -------- GATE=false -> bf16 out; GATE=true -> fused gating, f32 outputs ---------------
template<int CIN, int COUT, int SPLIT, bool GATE, bool IN1F>
__global__ __launch_bounds__(256) void bigconv_f(
    const u16* __restrict__ in0, const u16* __restrict__ in1b, const float* __restrict__ in1f,
    const float* __restrict__ W, const float* __restrict__ bias,
    void* __restrict__ out0v, void* __restrict__ out1v, const float* __restrict__ mem){
  __shared__ float lds[3][WW+2][CIN];
  constexpr int NJ = COUT/64;
  const int b = blockIdx.x / HH, y = blockIdx.x % HH;
  const int tid = threadIdx.x, lane = tid & 63, wave = tid >> 6;
  const f32x4 z4 = {0.f,0.f,0.f,0.f};

  for(int ky=0; ky<3; ky++){
    int ys = y + ky - 1;
    if(ys < 0 || ys >= HH){
      for(int c = tid; c < WW*CIN/4; c += 256){
        int px = c/(CIN/4), cb = (c%(CIN/4))*4;
        *(f32x4*)&lds[ky][px+1][cb] = z4;
      }
    } else {
      size_t base0 = (size_t)(b*HH + ys)*WW*SPLIT;
      size_t base1 = (size_t)(b*HH + ys)*WW*(CIN-SPLIT);
      for(int c8 = tid; c8 < WW*CIN/8; c8 += 256){
        int px = c8/(CIN/8), cb = (c8%(CIN/8))*8;
        float t[8];
        if(cb < SPLIT){
          short8 v = *(const short8*)&in0[base0 + (size_t)px*SPLIT + cb];
          #pragma unroll
          for(int j=0;j<8;j++) t[j] = bf2f((u16)v[j]);
        } else if constexpr (IN1F){
          const float* s = &in1f[base1 + (size_t)px*(CIN-SPLIT) + cb - SPLIT];
          #pragma unroll
          for(int j=0;j<8;j++) t[j] = s[j];
        } else {
          short8 v = *(const short8*)&in1b[base1 + (size_t)px*(CIN-SPLIT) + cb - SPLIT];
          #pragma unroll
          for(int j=0;j<8;j++) t[j] = bf2f((u16)v[j]);
        }
        #pragma unroll
        for(int j=0;j<8;j++) lds[ky][px+1][cb+j] = t[j];
      }
    }
    for(int c = tid; c < 2*(CIN/4); c += 256){
      int which = c/(CIN/4), cb = (c%(CIN/4))*4;
      *(f32x4*)&lds[ky][which ? (WW+1) : 0][cb] = z4;
    }
  }
  __syncthreads();

  float acc[12][NJ];
  #pragma unroll
  for(int i=0;i<12;i++)
    #pragma unroll
    for(int j=0;j<NJ;j++) acc[i][j] = 0.f;

  const int px0 = wave*12;
  for(int ky=0; ky<3; ky++)
  for(int kx=0; kx<3; kx++){
    const int kk = ky*3 + kx;
    for(int ci=0; ci<CIN; ci+=4){
      f32x4 a[12];
      #pragma unroll
      for(int i=0;i<12;i++) a[i] = *(const f32x4*)&lds[ky][px0+i+kx][ci];
      #pragma unroll
      for(int j=0;j<NJ;j++){
        #pragma unroll
        for(int qq=0;qq<4;qq++){
          float w = W[(size_t)(kk*CIN + ci + qq)*COUT + j*64 + lane];
          #pragma unroll
          for(int i=0;i<12;i++) acc[i][j] += a[i][qq]*w;
        }
      }
    }
  }

  if constexpr (!GATE){
    u16* out0 = (u16*)out0v;
    #pragma unroll
    for(int j=0;j<NJ;j++){
      float bs = bias[j*64 + lane];
      u16* op = out0 + (size_t)(b*HH + y)*WW*COUT + j*64 + lane;
      #pragma unroll
      for(int i=0;i<12;i++)
        op[(size_t)(px0+i)*COUT] = f2bf(acc[i][j] + bs);
    }
  } else {
    float* oh = (float*)out0v;
    float* om = (float*)out1v;
    float bo = bias[lane], bg = bias[64+lane], bgi = bias[128+lane];
    #pragma unroll
    for(int i=0;i<12;i++){
      size_t idx = ((size_t)(b*HH + y)*WW + px0 + i)*64 + lane;
      float mo = acc[i][0] + bo;
      float mg = acc[i][1] + bg;
      float gi = acc[i][2] + bgi;
      float mval = mem[idx];
      float si = 1.f/(1.f + __expf(-gi));
      float nm = (1.f - si)*mval + si*tanhf(mg);
      float nh = (1.f/(1.f + __expf(-mo)))*nm;
      oh[idx] = nh;
      om[idx] = nm;
    }
  }
}

// ---------------- launcher ----------------
extern "C" void kernel_launch(void* const* d_in, const int* in_sizes, int n_in,
                              void* d_out, int out_size, void* d_ws, size_t ws_size,
                              hipStream_t stream){
  (void)in_sizes; (void)n_in; (void)out_size; (void)ws_size;
  const float* h   = (const float*)d_in[0];
  const float* m   = (const float*)d_in[1];
  const float* Wq  = (const float*)d_in[2];  const float* bq  = (const float*)d_in[3];
  const float* Wk  = (const float*)d_in[4];  const float* bk  = (const float*)d_in[5];
  const float* Wk2 = (const float*)d_in[6];  const float* bk2 = (const float*)d_in[7];
  const float* Wv  = (const float*)d_in[8];  const float* bv  = (const float*)d_in[9];
  const float* Wv2 = (const float*)d_in[10]; const float* bv2 = (const float*)d_in[11];
  const float* Wz  = (const float*)d_in[12]; const float* bz  = (const float*)d_in[13];
  const float* Wm  = (const float*)d_in[14]; const float* bm  = (const float*)d_in[15];

  const size_t NPIX = (size_t)BB*NSEQ*DD;  // 1,179,648

  // workspace: 5 bf16 slots = 11.8 MB
  u16* ws = (u16*)d_ws;
  u16* slotA = ws;              // q;   later Z (low NPIX)
  u16* slotB = slotA + NPIX;    // k -> k_m; later Z (high NPIX)
  u16* slotC = slotB + NPIX;    // v -> v_m
  u16* slotD = slotC + NPIX;    // z_h
  u16* slotE = slotD + NPIX;    // z_m

  float* outh = (float*)d_out;          // new_h (f32!)
  float* outm = outh + NPIX;            // new_m (f32!)

  ConvPtrsF ph;
  ph.W[0]=Wq;  ph.W[1]=Wk;  ph.W[2]=Wv;
  ph.bias[0]=bq; ph.bias[1]=bk; ph.bias[2]=bv;
  ph.out[0]=slotA; ph.out[1]=slotB; ph.out[2]=slotC;
  conv64_f<3><<<dim3(BB*HH), 256, 0, stream>>>(h, ph);

  attn_valu<<<dim3(NSEQ/64, BB), 256, 0, stream>>>(slotA, slotB, slotC, slotD);

  ConvPtrsF pm;
  pm.W[0]=Wk2; pm.W[1]=Wv2; pm.W[2]=Wv2;
  pm.bias[0]=bk2; pm.bias[1]=bv2; pm.bias[2]=bv2;
  pm.out[0]=slotB; pm.out[1]=slotC; pm.out[2]=slotC;
  conv64_f<2><<<dim3(BB*HH), 256, 0, stream>>>(m, pm);

  attn_valu<<<dim3(NSEQ/64, BB), 256, 0, stream>>>(slotA, slotB, slotC, slotE);

  // Z = conv(concat(z_h, z_m)) -> bf16 into slotA..slotB (q, k_m dead)
  bigconv_f<128,128,64,false,false><<<dim3(BB*HH), 256, 0, stream>>>(
      slotD, slotE, (const float*)0, Wz, bz, (void*)slotA, (void*)0, (const float*)0);

  // combined = conv(concat(Z, h)); fused gating -> f32 outputs
  bigconv_f<192,192,128,true,true><<<dim3(BB*HH), 256, 0, stream>>>(
      slotA, (const u16*)0, h, Wm, bm, (void*)outh, (void*)outm, m);
}

// Round 7
// 346.273 us; speedup vs baseline: 8.5468x; 8.5468x over previous
//
#include <hip/hip_runtime.h>

#define BB 8
#define HH 48
#define WW 48
#define DD 64
#define NSEQ (HH*WW)   // 2304

typedef unsigned short u16;
typedef __attribute__((ext_vector_type(8))) short short8;
typedef __attribute__((ext_vector_type(4))) float f32x4;

__device__ __forceinline__ float bf2f(u16 u){ return __uint_as_float(((unsigned)u)<<16); }
__device__ __forceinline__ u16 f2bf(float f){
  unsigned u = __float_as_uint(f);
  return (u16)((u + 0x7fffu + ((u>>16)&1u)) >> 16);   // RNE
}
__device__ __forceinline__ f32x4 mfma16(short8 a, short8 b, f32x4 c){
  return __builtin_amdgcn_mfma_f32_16x16x32_bf16(a, b, c, 0, 0, 0);
}

// ------- weight transpose: src f32 [9][CI][CO] -> dst bf16 [9][CO][CI] ----------------
__global__ void wtrans_kernel(const float* __restrict__ src, u16* __restrict__ dst,
                              int CI, int CO){
  int total = 9*CI*CO;
  for(int i = blockIdx.x*blockDim.x + threadIdx.x; i < total; i += gridDim.x*blockDim.x){
    int kk  = i / (CI*CO);
    int rem = i % (CI*CO);
    int co  = rem / CI;
    int ci  = rem % CI;
    dst[i] = f2bf(src[kk*CI*CO + ci*CO + co]);
  }
}

// ---------------- multi-conv 64->64 (MFMA), f32 input staged to bf16 LDS --------------
struct ConvPtrs {
  const u16*   W[3];     // bf16 [9][co][ci]
  const float* bias[3];  // f32
  u16*         out[3];   // bf16
};

template<int NC>
__global__ __launch_bounds__(256) void conv64_mfma(const float* __restrict__ in, ConvPtrs p){
  const int SP = 72;                       // padded pixel stride (u16)
  __shared__ u16 lds[3][WW+2][SP];
  const int b = blockIdx.x / HH, y = blockIdx.x % HH;
  const int tid  = threadIdx.x;
  const int wave = tid >> 6, lane = tid & 63, g = lane >> 4, col = lane & 15;
  const short8 Z8 = {0,0,0,0,0,0,0,0};

  for(int ky=0; ky<3; ky++){
    int ys = y + ky - 1;
    const int NCH = WW*64/8;               // 384 chunks of 8
    if(ys < 0 || ys >= HH){
      for(int c8 = tid; c8 < NCH; c8 += 256){
        int px = c8 >> 3, cb = (c8 & 7)*8;
        *(short8*)&lds[ky][px+1][cb] = Z8;
      }
    } else {
      const float* rowp = in + (size_t)(b*HH + ys)*WW*64;
      for(int c8 = tid; c8 < NCH; c8 += 256){
        int px = c8 >> 3, cb = (c8 & 7)*8;
        short8 v;
        #pragma unroll
        for(int j=0;j<8;j++) v[j] = (short)f2bf(rowp[px*64 + cb + j]);
        *(short8*)&lds[ky][px+1][cb] = v;
      }
    }
    for(int c8 = tid; c8 < 16; c8 += 256){     // zero pad x=-1, x=W
      int which = c8 >> 3; int cb = (c8 & 7)*8;
      *(short8*)&lds[ky][which ? (WW+1) : 0][cb] = Z8;
    }
  }
  __syncthreads();

  const f32x4 zf = {0.f,0.f,0.f,0.f};
  f32x4 acc[3][NC];
  #pragma unroll
  for(int mt=0; mt<3; mt++)
    #pragma unroll
    for(int c=0; c<NC; c++) acc[mt][c] = zf;

  #pragma unroll
  for(int ky=0; ky<3; ky++)
  #pragma unroll
  for(int kx=0; kx<3; kx++)
  #pragma unroll
  for(int ks=0; ks<2; ks++){
    short8 a[3];
    #pragma unroll
    for(int mt=0; mt<3; mt++)
      a[mt] = *(const short8*)&lds[ky][mt*16 + col + kx][ks*32 + g*8];
    #pragma unroll
    for(int c=0; c<NC; c++){
      const u16* wp = p.W[c] + ((size_t)((ky*3+kx)*64) + (wave*16 + col))*64 + ks*32 + g*8;
      short8 bfr = *(const short8*)wp;
      #pragma unroll
      for(int mt=0; mt<3; mt++)
        acc[mt][c] = mfma16(a[mt], bfr, acc[mt][c]);
    }
  }

  #pragma unroll
  for(int c=0; c<NC; c++){
    int co = wave*16 + col;
    float bs = p.bias[c][co];
    u16* op = p.out[c] + ((size_t)(b*HH + y)*WW)*64 + co;
    #pragma unroll
    for(int mt=0; mt<3; mt++)
      #pragma unroll
      for(int r=0; r<4; r++){
        int px = mt*16 + g*4 + r;
        op[(size_t)px*64] = f2bf(acc[mt][c][r] + bs);
      }
  }
}

// ---------------- flash attention (MFMA): 64 q-rows per block, K/V tiles of 64 --------
__global__ __launch_bounds__(256) void attn_mfma(
    const u16* __restrict__ q, const u16* __restrict__ k, const u16* __restrict__ v,
    u16* __restrict__ z){
  __shared__ u16 Qs[64][72];
  __shared__ u16 Ks[64][72];
  __shared__ u16 Vts[64][72];   // transposed: [dim][key]
  __shared__ u16 Ps[64][72];    // per-wave-private 16-row strips
  const int qt = blockIdx.x, b = blockIdx.y;
  const int tid = threadIdx.x, wave = tid>>6, lane = tid&63, g = lane>>4, col = lane&15;

  const u16* qb = q + ((size_t)(b*NSEQ + qt*64))*DD;
  for(int c8 = tid; c8 < 64*DD/8; c8 += 256){
    int r = c8>>3, cb = (c8&7)*8;
    *(short8*)&Qs[r][cb] = *(const short8*)&qb[r*DD + cb];
  }

  const f32x4 zf = {0.f,0.f,0.f,0.f};
  f32x4 o[4];
  #pragma unroll
  for(int nt=0; nt<4; nt++) o[nt] = zf;
  float mstat[4], lstat[4];
  #pragma unroll
  for(int r=0; r<4; r++){ mstat[r] = -1e30f; lstat[r] = 0.f; }

  for(int kt=0; kt<NSEQ/64; kt++){
    __syncthreads();
    const u16* kb = k + ((size_t)(b*NSEQ + kt*64))*DD;
    const u16* vb = v + ((size_t)(b*NSEQ + kt*64))*DD;
    for(int c8 = tid; c8 < 512; c8 += 256){
      int r = c8>>3, cb = (c8&7)*8;
      *(short8*)&Ks[r][cb] = *(const short8*)&kb[r*DD + cb];
      short8 vv = *(const short8*)&vb[r*DD + cb];
      #pragma unroll
      for(int j=0; j<8; j++) Vts[cb+j][r] = (u16)vv[j];
    }
    __syncthreads();

    f32x4 s[4];
    #pragma unroll
    for(int nt=0; nt<4; nt++) s[nt] = zf;
    #pragma unroll
    for(int ks=0; ks<2; ks++){
      short8 aq = *(const short8*)&Qs[wave*16 + col][ks*32 + g*8];
      #pragma unroll
      for(int nt=0; nt<4; nt++){
        short8 bk = *(const short8*)&Ks[nt*16 + col][ks*32 + g*8];
        s[nt] = mfma16(aq, bk, s[nt]);
      }
    }

    #pragma unroll
    for(int r=0; r<4; r++){
      float mx = fmaxf(fmaxf(s[0][r], s[1][r]), fmaxf(s[2][r], s[3][r]));
      mx = fmaxf(mx, __shfl_xor(mx, 8));
      mx = fmaxf(mx, __shfl_xor(mx, 4));
      mx = fmaxf(mx, __shfl_xor(mx, 2));
      mx = fmaxf(mx, __shfl_xor(mx, 1));
      float mnew = fmaxf(mstat[r], mx);
      float scale = __expf(mstat[r] - mnew);
      mstat[r] = mnew;
      lstat[r] *= scale;
      #pragma unroll
      for(int nt=0; nt<4; nt++) o[nt][r] *= scale;
      float rs = 0.f;
      #pragma unroll
      for(int nt=0; nt<4; nt++){
        float pv = __expf(s[nt][r] - mnew);
        s[nt][r] = pv;
        rs += pv;
      }
      rs += __shfl_xor(rs, 8);
      rs += __shfl_xor(rs, 4);
      rs += __shfl_xor(rs, 2);
      rs += __shfl_xor(rs, 1);
      lstat[r] += rs;
      #pragma unroll
      for(int nt=0; nt<4; nt++)
        Ps[wave*16 + g*4 + r][nt*16 + col] = f2bf(s[nt][r]);
    }

    #pragma unroll
    for(int ks=0; ks<2; ks++){
      short8 ap = *(const short8*)&Ps[wave*16 + col][ks*32 + g*8];
      #pragma unroll
      for(int nt=0; nt<4; nt++){
        short8 bv = *(const short8*)&Vts[nt*16 + col][ks*32 + g*8];
        o[nt] = mfma16(ap, bv, o[nt]);
      }
    }
  }

  float inv[4];
  #pragma unroll
  for(int r=0; r<4; r++) inv[r] = 1.f/lstat[r];
  u16* zb = z + ((size_t)(b*NSEQ + qt*64 + wave*16))*DD;
  #pragma unroll
  for(int nt=0; nt<4; nt++)
    #pragma unroll
    for(int r=0; r<4; r++)
      zb[(g*4 + r)*DD + nt*16 + col] = f2bf(o[nt][r]*inv[r]);
}

// -------- big conv (MFMA, concat input): in0 bf16; in1 bf16 or f32; GATE -> f32 out ----
template<int CIN, int COUT, int SPLIT, bool GATE, bool IN1F>
__global__ __launch_bounds__(256) void bigconv_mfma(
    const u16* __restrict__ in0, const u16* __restrict__ in1b, const float* __restrict__ in1f,
    const u16* __restrict__ Wt, const float* __restrict__ bias,
    void* __restrict__ out0v, void* __restrict__ out1v, const float* __restrict__ mem){
  constexpr int SP  = CIN + 8;
  constexpr int NTW = COUT/64;
  __shared__ u16 lds[3][WW+2][SP];
  const int b = blockIdx.x / HH, y = blockIdx.x % HH;
  const int tid  = threadIdx.x;
  const int wave = tid >> 6, lane = tid & 63, g = lane >> 4, col = lane & 15;
  const short8 Z8 = {0,0,0,0,0,0,0,0};

  for(int ky=0; ky<3; ky++){
    int ys = y + ky - 1;
    const int NCH = WW*CIN/8;
    if(ys < 0 || ys >= HH){
      for(int c8 = tid; c8 < NCH; c8 += 256){
        int px = c8 / (CIN/8), cb = (c8 % (CIN/8))*8;
        *(short8*)&lds[ky][px+1][cb] = Z8;
      }
    } else {
      size_t base0 = (size_t)(b*HH + ys)*WW*SPLIT;
      size_t base1 = (size_t)(b*HH + ys)*WW*(CIN-SPLIT);
      for(int c8 = tid; c8 < NCH; c8 += 256){
        int px = c8 / (CIN/8), cb = (c8 % (CIN/8))*8;
        short8 val;
        if(cb < SPLIT){
          val = *(const short8*)&in0[base0 + (size_t)px*SPLIT + cb];
        } else if constexpr (IN1F){
          const float* s = &in1f[base1 + (size_t)px*(CIN-SPLIT) + cb - SPLIT];
          #pragma unroll
          for(int j=0;j<8;j++) val[j] = (short)f2bf(s[j]);
        } else {
          val = *(const short8*)&in1b[base1 + (size_t)px*(CIN-SPLIT) + cb - SPLIT];
        }
        *(short8*)&lds[ky][px+1][cb] = val;
      }
    }
    for(int c8 = tid; c8 < 2*(CIN/8); c8 += 256){
      int which = c8 / (CIN/8); int cb = (c8 % (CIN/8))*8;
      *(short8*)&lds[ky][which ? (WW+1) : 0][cb] = Z8;
    }
  }
  __syncthreads();

  const f32x4 zf = {0.f,0.f,0.f,0.f};
  f32x4 acc[3][NTW];
  #pragma unroll
  for(int mt=0; mt<3; mt++)
    #pragma unroll
    for(int i=0; i<NTW; i++) acc[mt][i] = zf;

  #pragma unroll
  for(int ky=0; ky<3; ky++)
  #pragma unroll
  for(int kx=0; kx<3; kx++)
  #pragma unroll
  for(int ks=0; ks<CIN/32; ks++){
    short8 a[3];
    #pragma unroll
    for(int mt=0; mt<3; mt++)
      a[mt] = *(const short8*)&lds[ky][mt*16 + col + kx][ks*32 + g*8];
    #pragma unroll
    for(int i=0; i<NTW; i++){
      int co0 = (wave + 4*i)*16;
      const u16* wp = Wt + ((size_t)((ky*3+kx)*COUT) + co0 + col)*CIN + ks*32 + g*8;
      short8 bfr = *(const short8*)wp;
      #pragma unroll
      for(int mt=0; mt<3; mt++)
        acc[mt][i] = mfma16(a[mt], bfr, acc[mt][i]);
    }
  }

  if constexpr (!GATE){
    u16* out0 = (u16*)out0v;
    #pragma unroll
    for(int i=0; i<NTW; i++){
      int co = (wave + 4*i)*16 + col;
      float bs = bias[co];
      u16* op = out0 + (size_t)(b*HH + y)*WW*COUT + co;
      #pragma unroll
      for(int mt=0; mt<3; mt++)
        #pragma unroll
        for(int r=0; r<4; r++){
          int px = mt*16 + g*4 + r;
          op[(size_t)px*COUT] = f2bf(acc[mt][i][r] + bs);
        }
    }
  } else {
    float* oh = (float*)out0v;
    float* om = (float*)out1v;
    int c = wave*16 + col;
    float bo = bias[c], bg = bias[64+c], bgi = bias[128+c];
    #pragma unroll
    for(int mt=0; mt<3; mt++)
      #pragma unroll
      for(int r=0; r<4; r++){
        int px = mt*16 + g*4 + r;
        size_t idx = ((size_t)(b*HH + y)*WW + px)*64 + c;
        float mo = acc[mt][0][r] + bo;
        float mg = acc[mt][1][r] + bg;
        float gi = acc[mt][2][r] + bgi;
        float mval = mem[idx];
        float si = 1.f/(1.f + __expf(-gi));
        float nm = (1.f - si)*mval + si*tanhf(mg);
        float nh = (1.f/(1.f + __expf(-mo)))*nm;
        oh[idx] = nh;
        om[idx] = nm;
      }
  }
}

// ---------------- launcher ----------------
extern "C" void kernel_launch(void* const* d_in, const int* in_sizes, int n_in,
                              void* d_out, int out_size, void* d_ws, size_t ws_size,
                              hipStream_t stream){
  (void)in_sizes; (void)n_in; (void)out_size; (void)ws_size;
  const float* h   = (const float*)d_in[0];
  const float* m   = (const float*)d_in[1];
  const float* Wq  = (const float*)d_in[2];  const float* bq  = (const float*)d_in[3];
  const float* Wk  = (const float*)d_in[4];  const float* bk  = (const float*)d_in[5];
  const float* Wk2 = (const float*)d_in[6];  const float* bk2 = (const float*)d_in[7];
  const float* Wv  = (const float*)d_in[8];  const float* bv  = (const float*)d_in[9];
  const float* Wv2 = (const float*)d_in[10]; const float* bv2 = (const float*)d_in[11];
  const float* Wz  = (const float*)d_in[12]; const float* bz  = (const float*)d_in[13];
  const float* Wm  = (const float*)d_in[14]; const float* bm  = (const float*)d_in[15];

  const size_t NPIX = (size_t)BB*NSEQ*DD;  // 1,179,648

  // workspace: 663,552 (weights) + 3*NPIX slots = 8.4 MB (< proven 11.8 MB)
  u16* ws = (u16*)d_ws;
  u16* WtQ  = ws + 0;
  u16* WtK  = ws + 36864;
  u16* WtK2 = ws + 73728;
  u16* WtV  = ws + 110592;
  u16* WtV2 = ws + 147456;
  u16* WtZ  = ws + 184320;       // 147456
  u16* WtM  = ws + 331776;       // 331776 -> ends at 663552
  u16* slotA = ws + 663552;      // q;  later Z low half
  u16* slotB = slotA + NPIX;     // k -> k_m; later Z high half
  u16* slotC = slotB + NPIX;     // v -> v_m
  u16* Zb    = slotA;            // 2*NPIX spanning A+B

  float* outh = (float*)d_out;   // final new_h (f32)
  float* outm = outh + NPIX;     // final new_m (f32)
  u16* zh = (u16*)d_out;                 // bf16 staging inside d_out (dead before final writes)
  u16* zm = zh + NPIX;

  wtrans_kernel<<<dim3(144), 256, 0, stream>>>(Wq,  WtQ,  64, 64);
  wtrans_kernel<<<dim3(144), 256, 0, stream>>>(Wk,  WtK,  64, 64);
  wtrans_kernel<<<dim3(144), 256, 0, stream>>>(Wk2, WtK2, 64, 64);
  wtrans_kernel<<<dim3(144), 256, 0, stream>>>(Wv,  WtV,  64, 64);
  wtrans_kernel<<<dim3(144), 256, 0, stream>>>(Wv2, WtV2, 64, 64);
  wtrans_kernel<<<dim3(288), 256, 0, stream>>>(Wz,  WtZ,  128, 128);
  wtrans_kernel<<<dim3(576), 256, 0, stream>>>(Wm,  WtM,  192, 192);

  ConvPtrs ph;
  ph.W[0]=WtQ;  ph.W[1]=WtK;  ph.W[2]=WtV;
  ph.bias[0]=bq; ph.bias[1]=bk; ph.bias[2]=bv;
  ph.out[0]=slotA; ph.out[1]=slotB; ph.out[2]=slotC;
  conv64_mfma<3><<<dim3(BB*HH), 256, 0, stream>>>(h, ph);

  attn_mfma<<<dim3(NSEQ/64, BB), 256, 0, stream>>>(slotA, slotB, slotC, zh);

  ConvPtrs pm;
  pm.W[0]=WtK2; pm.W[1]=WtV2; pm.W[2]=WtV2;
  pm.bias[0]=bk2; pm.bias[1]=bv2; pm.bias[2]=bv2;
  pm.out[0]=slotB; pm.out[1]=slotC; pm.out[2]=slotC;
  conv64_mfma<2><<<dim3(BB*HH), 256, 0, stream>>>(m, pm);

  attn_mfma<<<dim3(NSEQ/64, BB), 256, 0, stream>>>(slotA, slotB, slotC, zm);

  // Z = conv(concat(z_h, z_m)) -> bf16 into Zb (q,k_m slots dead)
  bigconv_mfma<128,128,64,false,false><<<dim3(BB*HH), 256, 0, stream>>>(
      zh, zm, (const float*)0, WtZ, bz, (void*)Zb, (void*)0, (const float*)0);

  // combined = conv(concat(Z, h)); fused gating -> f32 outputs
  bigconv_mfma<192,192,128,true,true><<<dim3(BB*HH), 256, 0, stream>>>(
      Zb, (const u16*)0, h, WtM, bm, (void*)outh, (void*)outm, m);
}

// Round 8
// 304.419 us; speedup vs baseline: 9.7219x; 1.1375x over previous
//
#include <hip/hip_runtime.h>

#define BB 8
#define HH 48
#define WW 48
#define DD 64
#define NSEQ (HH*WW)   // 2304

typedef unsigned short u16;
typedef __attribute__((ext_vector_type(8))) short short8;
typedef __attribute__((ext_vector_type(4))) float f32x4;

__device__ __forceinline__ float bf2f(u16 u){ return __uint_as_float(((unsigned)u)<<16); }
__device__ __forceinline__ u16 f2bf(float f){
  unsigned u = __float_as_uint(f);
  return (u16)((u + 0x7fffu + ((u>>16)&1u)) >> 16);   // RNE
}
__device__ __forceinline__ f32x4 mfma16(short8 a, short8 b, f32x4 c){
  return __builtin_amdgcn_mfma_f32_16x16x32_bf16(a, b, c, 0, 0, 0);
}

// ------- weight transpose: src f32 [9][CI][CO] -> dst bf16 [9][CO][CI] ----------------
__global__ void wtrans_kernel(const float* __restrict__ src, u16* __restrict__ dst,
                              int CI, int CO){
  int total = 9*CI*CO;
  for(int i = blockIdx.x*blockDim.x + threadIdx.x; i < total; i += gridDim.x*blockDim.x){
    int kk  = i / (CI*CO);
    int rem = i % (CI*CO);
    int co  = rem / CI;
    int ci  = rem % CI;
    dst[i] = f2bf(src[kk*CI*CO + ci*CO + co]);
  }
}

// ---------------- multi-conv 64->64 (MFMA), f32 input staged to bf16 LDS --------------
struct ConvPtrs {
  const u16*   W[3];     // bf16 [9][co][ci]
  const float* bias[3];  // f32
  u16*         out[3];   // bf16
};

template<int NC>
__global__ __launch_bounds__(256) void conv64_mfma(const float* __restrict__ in, ConvPtrs p){
  const int SP = 72;
  __shared__ u16 lds[3][WW+2][SP];
  const int b = blockIdx.x / HH, y = blockIdx.x % HH;
  const int tid  = threadIdx.x;
  const int wave = tid >> 6, lane = tid & 63, g = lane >> 4, col = lane & 15;
  const short8 Z8 = {0,0,0,0,0,0,0,0};

  for(int ky=0; ky<3; ky++){
    int ys = y + ky - 1;
    const int NCH = WW*64/8;
    if(ys < 0 || ys >= HH){
      for(int c8 = tid; c8 < NCH; c8 += 256){
        int px = c8 >> 3, cb = (c8 & 7)*8;
        *(short8*)&lds[ky][px+1][cb] = Z8;
      }
    } else {
      const float* rowp = in + (size_t)(b*HH + ys)*WW*64;
      for(int c8 = tid; c8 < NCH; c8 += 256){
        int px = c8 >> 3, cb = (c8 & 7)*8;
        short8 v;
        #pragma unroll
        for(int j=0;j<8;j++) v[j] = (short)f2bf(rowp[px*64 + cb + j]);
        *(short8*)&lds[ky][px+1][cb] = v;
      }
    }
    for(int c8 = tid; c8 < 16; c8 += 256){
      int which = c8 >> 3; int cb = (c8 & 7)*8;
      *(short8*)&lds[ky][which ? (WW+1) : 0][cb] = Z8;
    }
  }
  __syncthreads();

  const f32x4 zf = {0.f,0.f,0.f,0.f};
  f32x4 acc[3][NC];
  #pragma unroll
  for(int mt=0; mt<3; mt++)
    #pragma unroll
    for(int c=0; c<NC; c++) acc[mt][c] = zf;

  #pragma unroll
  for(int ky=0; ky<3; ky++)
  #pragma unroll
  for(int kx=0; kx<3; kx++)
  #pragma unroll
  for(int ks=0; ks<2; ks++){
    short8 a[3];
    #pragma unroll
    for(int mt=0; mt<3; mt++)
      a[mt] = *(const short8*)&lds[ky][mt*16 + col + kx][ks*32 + g*8];
    #pragma unroll
    for(int c=0; c<NC; c++){
      const u16* wp = p.W[c] + ((size_t)((ky*3+kx)*64) + (wave*16 + col))*64 + ks*32 + g*8;
      short8 bfr = *(const short8*)wp;
      #pragma unroll
      for(int mt=0; mt<3; mt++)
        acc[mt][c] = mfma16(a[mt], bfr, acc[mt][c]);
    }
  }

  #pragma unroll
  for(int c=0; c<NC; c++){
    int co = wave*16 + col;
    float bs = p.bias[c][co];
    u16* op = p.out[c] + ((size_t)(b*HH + y)*WW)*64 + co;
    #pragma unroll
    for(int mt=0; mt<3; mt++)
      #pragma unroll
      for(int r=0; r<4; r++){
        int px = mt*16 + g*4 + r;
        op[(size_t)px*64] = f2bf(acc[mt][c][r] + bs);
      }
  }
}

// ------- fused dual flash attention: 8 waves, waves 0-3 stream h, 4-7 stream m --------
__global__ __launch_bounds__(512) void attn2_mfma(
    const u16* __restrict__ q,
    const u16* __restrict__ kh, const u16* __restrict__ vh,
    const u16* __restrict__ km2, const u16* __restrict__ vm2,
    u16* __restrict__ zh, u16* __restrict__ zm){
  __shared__ u16 Ks [2][64][72];
  __shared__ u16 Vts[2][64][72];   // [stream][d][key]
  __shared__ u16 Ps [2][64][72];
  const int qt = blockIdx.x, b = blockIdx.y;
  const int tid = threadIdx.x, wave = tid>>6, lane = tid&63;
  const int g = lane>>4, col = lane&15;
  const int strip = wave & 3, s = wave >> 2;

  // Q fragments straight from global (row = qt*64 + strip*16 + col)
  const u16* qp = q + ((size_t)(b*NSEQ + qt*64 + strip*16 + col))*DD;
  short8 aq0 = *(const short8*)&qp[g*8];
  short8 aq1 = *(const short8*)&qp[32 + g*8];

  const int r0 = tid>>3, cb0 = (tid&7)*8;      // staging chunk (512 chunks, 1/thread)
  const size_t tb = (size_t)(b*NSEQ)*DD;

  short8 paK, paV, paKm, paVm, pbK, pbV, pbKm, pbVm;

  const f32x4 zf = {0.f,0.f,0.f,0.f};
  f32x4 o[4];
  #pragma unroll
  for(int nt=0; nt<4; nt++) o[nt] = zf;
  float mst[4], lst[4];
  #pragma unroll
  for(int r=0; r<4; r++){ mst[r] = -1e30f; lst[r] = 0.f; }

#define LOADSET(pk_, pv_, pkm_, pvm_, kt_) {                        \
    size_t off = tb + (size_t)(kt_)*64*DD + (size_t)r0*DD + cb0;    \
    pk_  = *(const short8*)&kh [off];                               \
    pv_  = *(const short8*)&vh [off];                               \
    pkm_ = *(const short8*)&km2[off];                               \
    pvm_ = *(const short8*)&vm2[off];                               \
  }
#define STORESET(pk_, pv_, pkm_, pvm_) {                            \
    *(short8*)&Ks[0][r0][cb0] = pk_;                                \
    *(short8*)&Ks[1][r0][cb0] = pkm_;                               \
    _Pragma("unroll")                                               \
    for(int j=0;j<8;j++){                                           \
      Vts[0][cb0+j][r0] = (u16)pv_[j];                              \
      Vts[1][cb0+j][r0] = (u16)pvm_[j];                             \
    }                                                               \
  }
#define COMPUTE() {                                                 \
    f32x4 sv[4];                                                    \
    _Pragma("unroll")                                               \
    for(int nt=0; nt<4; nt++){                                      \
      sv[nt] = zf;                                                  \
      short8 bk0 = *(const short8*)&Ks[s][nt*16 + col][g*8];        \
      sv[nt] = mfma16(aq0, bk0, sv[nt]);                            \
      short8 bk1 = *(const short8*)&Ks[s][nt*16 + col][32 + g*8];   \
      sv[nt] = mfma16(aq1, bk1, sv[nt]);                            \
    }                                                               \
    _Pragma("unroll")                                               \
    for(int r=0; r<4; r++){                                         \
      float mx = fmaxf(fmaxf(sv[0][r], sv[1][r]), fmaxf(sv[2][r], sv[3][r])); \
      mx = fmaxf(mx, __shfl_xor(mx, 8));                            \
      mx = fmaxf(mx, __shfl_xor(mx, 4));                            \
      mx = fmaxf(mx, __shfl_xor(mx, 2));                            \
      mx = fmaxf(mx, __shfl_xor(mx, 1));                            \
      float mnew = fmaxf(mst[r], mx);                               \
      float scale = __expf(mst[r] - mnew);                          \
      mst[r] = mnew;                                                \
      lst[r] *= scale;                                              \
      _Pragma("unroll")                                             \
      for(int nt=0; nt<4; nt++) o[nt][r] *= scale;                  \
      float rs = 0.f;                                               \
      _Pragma("unroll")                                             \
      for(int nt=0; nt<4; nt++){                                    \
        float pv = __expf(sv[nt][r] - mnew);                        \
        sv[nt][r] = pv;                                             \
        rs += pv;                                                   \
      }                                                             \
      rs += __shfl_xor(rs, 8);                                      \
      rs += __shfl_xor(rs, 4);                                      \
      rs += __shfl_xor(rs, 2);                                      \
      rs += __shfl_xor(rs, 1);                                      \
      lst[r] += rs;                                                 \
      _Pragma("unroll")                                             \
      for(int nt=0; nt<4; nt++)                                     \
        Ps[s][strip*16 + g*4 + r][nt*16 + col] = f2bf(sv[nt][r]);   \
    }                                                               \
    _Pragma("unroll")                                               \
    for(int ks=0; ks<2; ks++){                                      \
      short8 ap = *(const short8*)&Ps[s][strip*16 + col][ks*32 + g*8]; \
      _Pragma("unroll")                                             \
      for(int nt=0; nt<4; nt++){                                    \
        short8 bv = *(const short8*)&Vts[s][nt*16 + col][ks*32 + g*8]; \
        o[nt] = mfma16(ap, bv, o[nt]);                              \
      }                                                             \
    }                                                               \
  }

  LOADSET(paK, paV, paKm, paVm, 0);
  for(int kt = 0; kt < NSEQ/64; kt += 2){
    LOADSET(pbK, pbV, pbKm, pbVm, kt+1);
    __syncthreads();
    STORESET(paK, paV, paKm, paVm);
    __syncthreads();
    COMPUTE();
    if(kt+2 < NSEQ/64) LOADSET(paK, paV, paKm, paVm, kt+2);
    __syncthreads();
    STORESET(pbK, pbV, pbKm, pbVm);
    __syncthreads();
    COMPUTE();
  }

  float inv[4];
  #pragma unroll
  for(int r=0; r<4; r++) inv[r] = 1.f/lst[r];
  u16* zout = s ? zm : zh;
  u16* zb = zout + ((size_t)(b*NSEQ + qt*64 + strip*16))*DD;
  #pragma unroll
  for(int nt=0; nt<4; nt++)
    #pragma unroll
    for(int r=0; r<4; r++)
      zb[(g*4 + r)*DD + nt*16 + col] = f2bf(o[nt][r]*inv[r]);
#undef LOADSET
#undef STORESET
#undef COMPUTE
}

// -------- big conv (MFMA, concat input): in0 bf16; in1 bf16 or f32; GATE -> f32 out ----
template<int CIN, int COUT, int SPLIT, bool GATE, bool IN1F>
__global__ __launch_bounds__(256) void bigconv_mfma(
    const u16* __restrict__ in0, const u16* __restrict__ in1b, const float* __restrict__ in1f,
    const u16* __restrict__ Wt, const float* __restrict__ bias,
    void* __restrict__ out0v, void* __restrict__ out1v, const float* __restrict__ mem){
  constexpr int SP  = CIN + 8;
  constexpr int NTW = COUT/64;
  __shared__ u16 lds[3][WW+2][SP];
  const int b = blockIdx.x / HH, y = blockIdx.x % HH;
  const int tid  = threadIdx.x;
  const int wave = tid >> 6, lane = tid & 63, g = lane >> 4, col = lane & 15;
  const short8 Z8 = {0,0,0,0,0,0,0,0};

  for(int ky=0; ky<3; ky++){
    int ys = y + ky - 1;
    const int NCH = WW*CIN/8;
    if(ys < 0 || ys >= HH){
      for(int c8 = tid; c8 < NCH; c8 += 256){
        int px = c8 / (CIN/8), cb = (c8 % (CIN/8))*8;
        *(short8*)&lds[ky][px+1][cb] = Z8;
      }
    } else {
      size_t base0 = (size_t)(b*HH + ys)*WW*SPLIT;
      size_t base1 = (size_t)(b*HH + ys)*WW*(CIN-SPLIT);
      for(int c8 = tid; c8 < NCH; c8 += 256){
        int px = c8 / (CIN/8), cb = (c8 % (CIN/8))*8;
        short8 val;
        if(cb < SPLIT){
          val = *(const short8*)&in0[base0 + (size_t)px*SPLIT + cb];
        } else if constexpr (IN1F){
          const float* sp = &in1f[base1 + (size_t)px*(CIN-SPLIT) + cb - SPLIT];
          #pragma unroll
          for(int j=0;j<8;j++) val[j] = (short)f2bf(sp[j]);
        } else {
          val = *(const short8*)&in1b[base1 + (size_t)px*(CIN-SPLIT) + cb - SPLIT];
        }
        *(short8*)&lds[ky][px+1][cb] = val;
      }
    }
    for(int c8 = tid; c8 < 2*(CIN/8); c8 += 256){
      int which = c8 / (CIN/8); int cb = (c8 % (CIN/8))*8;
      *(short8*)&lds[ky][which ? (WW+1) : 0][cb] = Z8;
    }
  }
  __syncthreads();

  const f32x4 zf = {0.f,0.f,0.f,0.f};
  f32x4 acc[3][NTW];
  #pragma unroll
  for(int mt=0; mt<3; mt++)
    #pragma unroll
    for(int i=0; i<NTW; i++) acc[mt][i] = zf;

  #pragma unroll
  for(int ky=0; ky<3; ky++)
  #pragma unroll
  for(int kx=0; kx<3; kx++)
  #pragma unroll
  for(int ks=0; ks<CIN/32; ks++){
    short8 a[3];
    #pragma unroll
    for(int mt=0; mt<3; mt++)
      a[mt] = *(const short8*)&lds[ky][mt*16 + col + kx][ks*32 + g*8];
    #pragma unroll
    for(int i=0; i<NTW; i++){
      int co0 = (wave + 4*i)*16;
      const u16* wp = Wt + ((size_t)((ky*3+kx)*COUT) + co0 + col)*CIN + ks*32 + g*8;
      short8 bfr = *(const short8*)wp;
      #pragma unroll
      for(int mt=0; mt<3; mt++)
        acc[mt][i] = mfma16(a[mt], bfr, acc[mt][i]);
    }
  }

  if constexpr (!GATE){
    u16* out0 = (u16*)out0v;
    #pragma unroll
    for(int i=0; i<NTW; i++){
      int co = (wave + 4*i)*16 + col;
      float bs = bias[co];
      u16* op = out0 + (size_t)(b*HH + y)*WW*COUT + co;
      #pragma unroll
      for(int mt=0; mt<3; mt++)
        #pragma unroll
        for(int r=0; r<4; r++){
          int px = mt*16 + g*4 + r;
          op[(size_t)px*COUT] = f2bf(acc[mt][i][r] + bs);
        }
    }
  } else {
    float* oh = (float*)out0v;
    float* om = (float*)out1v;
    int c = wave*16 + col;
    float bo = bias[c], bg = bias[64+c], bgi = bias[128+c];
    #pragma unroll
    for(int mt=0; mt<3; mt++)
      #pragma unroll
      for(int r=0; r<4; r++){
        int px = mt*16 + g*4 + r;
        size_t idx = ((size_t)(b*HH + y)*WW + px)*64 + c;
        float mo = acc[mt][0][r] + bo;
        float mg = acc[mt][1][r] + bg;
        float gi = acc[mt][2][r] + bgi;
        float mval = mem[idx];
        float si = 1.f/(1.f + __expf(-gi));
        float nm = (1.f - si)*mval + si*tanhf(mg);
        float nh = (1.f/(1.f + __expf(-mo)))*nm;
        oh[idx] = nh;
        om[idx] = nm;
      }
  }
}

// ---------------- launcher ----------------
extern "C" void kernel_launch(void* const* d_in, const int* in_sizes, int n_in,
                              void* d_out, int out_size, void* d_ws, size_t ws_size,
                              hipStream_t stream){
  (void)in_sizes; (void)n_in; (void)out_size; (void)ws_size;
  const float* h   = (const float*)d_in[0];
  const float* m   = (const float*)d_in[1];
  const float* Wq  = (const float*)d_in[2];  const float* bq  = (const float*)d_in[3];
  const float* Wk  = (const float*)d_in[4];  const float* bk  = (const float*)d_in[5];
  const float* Wk2 = (const float*)d_in[6];  const float* bk2 = (const float*)d_in[7];
  const float* Wv  = (const float*)d_in[8];  const float* bv  = (const float*)d_in[9];
  const float* Wv2 = (const float*)d_in[10]; const float* bv2 = (const float*)d_in[11];
  const float* Wz  = (const float*)d_in[12]; const float* bz  = (const float*)d_in[13];
  const float* Wm  = (const float*)d_in[14]; const float* bm  = (const float*)d_in[15];

  const size_t NPIX = (size_t)BB*NSEQ*DD;  // 1,179,648

  // workspace: weights (663,552) + 5 slots = 13.1 MB (rounds 1/3 proved >=22 MB safe)
  u16* ws = (u16*)d_ws;
  u16* WtQ  = ws + 0;
  u16* WtK  = ws + 36864;
  u16* WtK2 = ws + 73728;
  u16* WtV  = ws + 110592;
  u16* WtV2 = ws + 147456;
  u16* WtZ  = ws + 184320;       // 147456
  u16* WtM  = ws + 331776;       // 331776 -> ends at 663552
  u16* slotA = ws + 663552;      // q;   later Z low half
  u16* slotB = slotA + NPIX;     // k_h; later Z high half
  u16* slotC = slotB + NPIX;     // v_h
  u16* slotD = slotC + NPIX;     // k_m
  u16* slotE = slotD + NPIX;     // v_m
  u16* Zb    = slotA;            // 2*NPIX spanning A+B

  float* outh = (float*)d_out;   // final new_h (f32)
  float* outm = outh + NPIX;     // final new_m (f32)
  u16* zh = (u16*)d_out;         // bf16 staging inside d_out (dead before final writes)
  u16* zm = zh + NPIX;

  wtrans_kernel<<<dim3(144), 256, 0, stream>>>(Wq,  WtQ,  64, 64);
  wtrans_kernel<<<dim3(144), 256, 0, stream>>>(Wk,  WtK,  64, 64);
  wtrans_kernel<<<dim3(144), 256, 0, stream>>>(Wk2, WtK2, 64, 64);
  wtrans_kernel<<<dim3(144), 256, 0, stream>>>(Wv,  WtV,  64, 64);
  wtrans_kernel<<<dim3(144), 256, 0, stream>>>(Wv2, WtV2, 64, 64);
  wtrans_kernel<<<dim3(288), 256, 0, stream>>>(Wz,  WtZ,  128, 128);
  wtrans_kernel<<<dim3(576), 256, 0, stream>>>(Wm,  WtM,  192, 192);

  ConvPtrs ph;
  ph.W[0]=WtQ;  ph.W[1]=WtK;  ph.W[2]=WtV;
  ph.bias[0]=bq; ph.bias[1]=bk; ph.bias[2]=bv;
  ph.out[0]=slotA; ph.out[1]=slotB; ph.out[2]=slotC;
  conv64_mfma<3><<<dim3(BB*HH), 256, 0, stream>>>(h, ph);

  ConvPtrs pm;
  pm.W[0]=WtK2; pm.W[1]=WtV2; pm.W[2]=WtV2;
  pm.bias[0]=bk2; pm.bias[1]=bv2; pm.bias[2]=bv2;
  pm.out[0]=slotD; pm.out[1]=slotE; pm.out[2]=slotE;
  conv64_mfma<2><<<dim3(BB*HH), 256, 0, stream>>>(m, pm);

  // fused dual attention -> z_h, z_m staged bf16 in d_out
  attn2_mfma<<<dim3(NSEQ/64, BB), 512, 0, stream>>>(
      slotA, slotB, slotC, slotD, slotE, zh, zm);

  // Z = conv(concat(z_h, z_m)) -> bf16 into Zb (q, k_h slots dead)
  bigconv_mfma<128,128,64,false,false><<<dim3(BB*HH), 256, 0, stream>>>(
      zh, zm, (const float*)0, WtZ, bz, (void*)Zb, (void*)0, (const float*)0);

  // combined = conv(concat(Z, h)); fused gating -> f32 outputs
  bigconv_mfma<192,192,128,true,true><<<dim3(BB*HH), 256, 0, stream>>>(
      Zb, (const u16*)0, h, WtM, bm, (void*)outh, (void*)outm, m);
}

// Round 9
// 263.656 us; speedup vs baseline: 11.2250x; 1.1546x over previous
//
#include <hip/hip_runtime.h>

#define BB 8
#define HH 48
#define WW 48
#define DD 64
#define NSEQ (HH*WW)   // 2304

typedef unsigned short u16;
typedef unsigned long long u64;
typedef __attribute__((ext_vector_type(8))) short short8;
typedef __attribute__((ext_vector_type(4))) float f32x4;

__device__ __forceinline__ float bf2f(u16 u){ return __uint_as_float(((unsigned)u)<<16); }
__device__ __forceinline__ u16 f2bf(float f){
  unsigned u = __float_as_uint(f);
  return (u16)((u + 0x7fffu + ((u>>16)&1u)) >> 16);   // RNE
}
__device__ __forceinline__ f32x4 mfma16(short8 a, short8 b, f32x4 c){
  return __builtin_amdgcn_mfma_f32_16x16x32_bf16(a, b, c, 0, 0, 0);
}

// ------- weight transpose: src f32 [9][CI][CO] -> dst bf16 [9][CO][CI] ----------------
__global__ void wtrans_kernel(const float* __restrict__ src, u16* __restrict__ dst,
                              int CI, int CO){
  int total = 9*CI*CO;
  for(int i = blockIdx.x*blockDim.x + threadIdx.x; i < total; i += gridDim.x*blockDim.x){
    int kk  = i / (CI*CO);
    int rem = i % (CI*CO);
    int co  = rem / CI;
    int ci  = rem % CI;
    dst[i] = f2bf(src[kk*CI*CO + ci*CO + co]);
  }
}

// ---------------- multi-conv 64->64 (MFMA); optional transposed [b][co][seq] output ----
struct ConvPtrs {
  const u16*   W[3];     // bf16 [9][co][ci]
  const float* bias[3];  // f32
  u16*         out[3];   // bf16
  int          vt[3];    // 1 -> write transposed [b][co][seq]
};

template<int NC>
__global__ __launch_bounds__(256) void conv64_mfma(const float* __restrict__ in, ConvPtrs p){
  const int SP = 72;
  __shared__ u16 lds[3][WW+2][SP];
  const int b = blockIdx.x / HH, y = blockIdx.x % HH;
  const int tid  = threadIdx.x;
  const int wave = tid >> 6, lane = tid & 63, g = lane >> 4, col = lane & 15;
  const short8 Z8 = {0,0,0,0,0,0,0,0};

  for(int ky=0; ky<3; ky++){
    int ys = y + ky - 1;
    const int NCH = WW*64/8;
    if(ys < 0 || ys >= HH){
      for(int c8 = tid; c8 < NCH; c8 += 256){
        int px = c8 >> 3, cb = (c8 & 7)*8;
        *(short8*)&lds[ky][px+1][cb] = Z8;
      }
    } else {
      const float* rowp = in + (size_t)(b*HH + ys)*WW*64;
      for(int c8 = tid; c8 < NCH; c8 += 256){
        int px = c8 >> 3, cb = (c8 & 7)*8;
        short8 v;
        #pragma unroll
        for(int j=0;j<8;j++) v[j] = (short)f2bf(rowp[px*64 + cb + j]);
        *(short8*)&lds[ky][px+1][cb] = v;
      }
    }
    for(int c8 = tid; c8 < 16; c8 += 256){
      int which = c8 >> 3; int cb = (c8 & 7)*8;
      *(short8*)&lds[ky][which ? (WW+1) : 0][cb] = Z8;
    }
  }
  __syncthreads();

  const f32x4 zf = {0.f,0.f,0.f,0.f};
  f32x4 acc[3][NC];
  #pragma unroll
  for(int mt=0; mt<3; mt++)
    #pragma unroll
    for(int c=0; c<NC; c++) acc[mt][c] = zf;

  #pragma unroll
  for(int ky=0; ky<3; ky++)
  #pragma unroll
  for(int kx=0; kx<3; kx++)
  #pragma unroll
  for(int ks=0; ks<2; ks++){
    short8 a[3];
    #pragma unroll
    for(int mt=0; mt<3; mt++)
      a[mt] = *(const short8*)&lds[ky][mt*16 + col + kx][ks*32 + g*8];
    #pragma unroll
    for(int c=0; c<NC; c++){
      const u16* wp = p.W[c] + ((size_t)((ky*3+kx)*64) + (wave*16 + col))*64 + ks*32 + g*8;
      short8 bfr = *(const short8*)wp;
      #pragma unroll
      for(int mt=0; mt<3; mt++)
        acc[mt][c] = mfma16(a[mt], bfr, acc[mt][c]);
    }
  }

  #pragma unroll
  for(int c=0; c<NC; c++){
    int co = wave*16 + col;
    float bs = p.bias[c][co];
    if(p.vt[c]){
      // transposed: out[b][co][y*WW + px]; px runs contiguous -> pack 4 u16 per 8B store
      u16* op = p.out[c] + ((size_t)(b*64 + co))*NSEQ + (size_t)y*WW;
      #pragma unroll
      for(int mt=0; mt<3; mt++){
        int px = mt*16 + g*4;
        u64 pk =  (u64)f2bf(acc[mt][c][0] + bs)
               | ((u64)f2bf(acc[mt][c][1] + bs) << 16)
               | ((u64)f2bf(acc[mt][c][2] + bs) << 32)
               | ((u64)f2bf(acc[mt][c][3] + bs) << 48);
        *(u64*)&op[px] = pk;
      }
    } else {
      u16* op = p.out[c] + ((size_t)(b*HH + y)*WW)*64 + co;
      #pragma unroll
      for(int mt=0; mt<3; mt++)
        #pragma unroll
        for(int r=0; r<4; r++){
          int px = mt*16 + g*4 + r;
          op[(size_t)px*64] = f2bf(acc[mt][c][r] + bs);
        }
    }
  }
}

// ------- fused dual flash attention: QBLK=32, 4 waves (2 strips x 2 streams) ----------
// V inputs are pre-transposed [b][d][seq]; K inputs row-major [b][seq][d].
__global__ __launch_bounds__(256) void attn2_mfma(
    const u16* __restrict__ q,
    const u16* __restrict__ kh, const u16* __restrict__ vhT,
    const u16* __restrict__ km2, const u16* __restrict__ vmT,
    u16* __restrict__ zh, u16* __restrict__ zm){
  __shared__ u16 Ks [2][64][72];
  __shared__ u16 Vts[2][64][72];   // [stream][d][key] (already transposed)
  __shared__ u16 Ps [2][32][72];
  const int qt = blockIdx.x, b = blockIdx.y;
  const int tid = threadIdx.x, wave = tid>>6, lane = tid&63;
  const int g = lane>>4, col = lane&15;
  const int strip = wave & 1, s = wave >> 1;

  // Q fragments straight from global (row = qt*32 + strip*16 + col)
  const u16* qp = q + ((size_t)(b*NSEQ + qt*32 + strip*16 + col))*DD;
  short8 aq0 = *(const short8*)&qp[g*8];
  short8 aq1 = *(const short8*)&qp[32 + g*8];

  // staging chunks: per tensor 512 chunks of short8; 256 threads -> 2 each
  const int r0a = tid>>3,        cb0a = (tid&7)*8;
  const int r0b = (tid+256)>>3,  cb0b = (tid&7)*8;   // (tid+256)&7 == tid&7
  const size_t tb  = (size_t)(b*NSEQ)*DD;
  const size_t tbT = (size_t)(b*64)*NSEQ;

  short8 paK0,paK1,paV0,paV1,paKm0,paKm1,paVm0,paVm1;
  short8 pbK0,pbK1,pbV0,pbV1,pbKm0,pbKm1,pbVm0,pbVm1;

  const f32x4 zf = {0.f,0.f,0.f,0.f};
  f32x4 o[4];
  #pragma unroll
  for(int nt=0; nt<4; nt++) o[nt] = zf;
  float mst[4], lst[4];
  #pragma unroll
  for(int r=0; r<4; r++){ mst[r] = -1e30f; lst[r] = 0.f; }

#define LOADSET(K0,K1,V0,V1,Km0,Km1,Vm0,Vm1, kt_) {                        \
    size_t offK0 = tb + (size_t)(kt_)*64*DD + (size_t)r0a*DD + cb0a;       \
    size_t offK1 = tb + (size_t)(kt_)*64*DD + (size_t)r0b*DD + cb0b;       \
    size_t offV0 = tbT + (size_t)r0a*NSEQ + (size_t)(kt_)*64 + cb0a;       \
    size_t offV1 = tbT + (size_t)r0b*NSEQ + (size_t)(kt_)*64 + cb0b;       \
    K0  = *(const short8*)&kh [offK0];  K1  = *(const short8*)&kh [offK1]; \
    Km0 = *(const short8*)&km2[offK0];  Km1 = *(const short8*)&km2[offK1]; \
    V0  = *(const short8*)&vhT[offV0];  V1  = *(const short8*)&vhT[offV1]; \
    Vm0 = *(const short8*)&vmT[offV0];  Vm1 = *(const short8*)&vmT[offV1]; \
  }
#define STORESET(K0,K1,V0,V1,Km0,Km1,Vm0,Vm1) {                            \
    *(short8*)&Ks [0][r0a][cb0a] = K0;   *(short8*)&Ks [0][r0b][cb0b] = K1; \
    *(short8*)&Ks [1][r0a][cb0a] = Km0;  *(short8*)&Ks [1][r0b][cb0b] = Km1;\
    *(short8*)&Vts[0][r0a][cb0a] = V0;   *(short8*)&Vts[0][r0b][cb0b] = V1; \
    *(short8*)&Vts[1][r0a][cb0a] = Vm0;  *(short8*)&Vts[1][r0b][cb0b] = Vm1;\
  }
#define COMPUTE() {                                                 \
    __builtin_amdgcn_s_setprio(1);                                  \
    f32x4 sv[4];                                                    \
    _Pragma("unroll")                                               \
    for(int nt=0; nt<4; nt++){                                      \
      sv[nt] = zf;                                                  \
      short8 bk0 = *(const short8*)&Ks[s][nt*16 + col][g*8];        \
      sv[nt] = mfma16(aq0, bk0, sv[nt]);                            \
      short8 bk1 = *(const short8*)&Ks[s][nt*16 + col][32 + g*8];   \
      sv[nt] = mfma16(aq1, bk1, sv[nt]);                            \
    }                                                               \
    _Pragma("unroll")                                               \
    for(int r=0; r<4; r++){                                         \
      float mx = fmaxf(fmaxf(sv[0][r], sv[1][r]), fmaxf(sv[2][r], sv[3][r])); \
      mx = fmaxf(mx, __shfl_xor(mx, 8));                            \
      mx = fmaxf(mx, __shfl_xor(mx, 4));                            \
      mx = fmaxf(mx, __shfl_xor(mx, 2));                            \
      mx = fmaxf(mx, __shfl_xor(mx, 1));                            \
      float mnew = fmaxf(mst[r], mx);                               \
      float scale = __expf(mst[r] - mnew);                          \
      mst[r] = mnew;                                                \
      lst[r] *= scale;                                              \
      _Pragma("unroll")                                             \
      for(int nt=0; nt<4; nt++) o[nt][r] *= scale;                  \
      float rs = 0.f;                                               \
      _Pragma("unroll")                                             \
      for(int nt=0; nt<4; nt++){                                    \
        float pv = __expf(sv[nt][r] - mnew);                        \
        sv[nt][r] = pv;                                             \
        rs += pv;                                                   \
      }                                                             \
      rs += __shfl_xor(rs, 8);                                      \
      rs += __shfl_xor(rs, 4);                                      \
      rs += __shfl_xor(rs, 2);                                      \
      rs += __shfl_xor(rs, 1);                                      \
      lst[r] += rs;                                                 \
      _Pragma("unroll")                                             \
      for(int nt=0; nt<4; nt++)                                     \
        Ps[s][strip*16 + g*4 + r][nt*16 + col] = f2bf(sv[nt][r]);   \
    }                                                               \
    _Pragma("unroll")                                               \
    for(int ks=0; ks<2; ks++){                                      \
      short8 ap = *(const short8*)&Ps[s][strip*16 + col][ks*32 + g*8]; \
      _Pragma("unroll")                                             \
      for(int nt=0; nt<4; nt++){                                    \
        short8 bv = *(const short8*)&Vts[s][nt*16 + col][ks*32 + g*8]; \
        o[nt] = mfma16(ap, bv, o[nt]);                              \
      }                                                             \
    }                                                               \
    __builtin_amdgcn_s_setprio(0);                                  \
  }

  LOADSET(paK0,paK1,paV0,paV1,paKm0,paKm1,paVm0,paVm1, 0);
  for(int kt = 0; kt < NSEQ/64; kt += 2){
    LOADSET(pbK0,pbK1,pbV0,pbV1,pbKm0,pbKm1,pbVm0,pbVm1, kt+1);
    __syncthreads();
    STORESET(paK0,paK1,paV0,paV1,paKm0,paKm1,paVm0,paVm1);
    __syncthreads();
    COMPUTE();
    if(kt+2 < NSEQ/64) LOADSET(paK0,paK1,paV0,paV1,paKm0,paKm1,paVm0,paVm1, kt+2);
    __syncthreads();
    STORESET(pbK0,pbK1,pbV0,pbV1,pbKm0,pbKm1,pbVm0,pbVm1);
    __syncthreads();
    COMPUTE();
  }

  float inv[4];
  #pragma unroll
  for(int r=0; r<4; r++) inv[r] = 1.f/lst[r];
  u16* zout = s ? zm : zh;
  u16* zb = zout + ((size_t)(b*NSEQ + qt*32 + strip*16))*DD;
  #pragma unroll
  for(int nt=0; nt<4; nt++)
    #pragma unroll
    for(int r=0; r<4; r++)
      zb[(g*4 + r)*DD + nt*16 + col] = f2bf(o[nt][r]*inv[r]);
#undef LOADSET
#undef STORESET
#undef COMPUTE
}

// -------- big conv (MFMA, concat input): in0 bf16; in1 bf16 or f32; GATE -> f32 out ----
template<int CIN, int COUT, int SPLIT, bool GATE, bool IN1F>
__global__ __launch_bounds__(256) void bigconv_mfma(
    const u16* __restrict__ in0, const u16* __restrict__ in1b, const float* __restrict__ in1f,
    const u16* __restrict__ Wt, const float* __restrict__ bias,
    void* __restrict__ out0v, void* __restrict__ out1v, const float* __restrict__ mem){
  constexpr int SP  = CIN + 8;
  constexpr int NTW = COUT/64;
  __shared__ u16 lds[3][WW+2][SP];
  const int b = blockIdx.x / HH, y = blockIdx.x % HH;
  const int tid  = threadIdx.x;
  const int wave = tid >> 6, lane = tid & 63, g = lane >> 4, col = lane & 15;
  const short8 Z8 = {0,0,0,0,0,0,0,0};

  for(int ky=0; ky<3; ky++){
    int ys = y + ky - 1;
    const int NCH = WW*CIN/8;
    if(ys < 0 || ys >= HH){
      for(int c8 = tid; c8 < NCH; c8 += 256){
        int px = c8 / (CIN/8), cb = (c8 % (CIN/8))*8;
        *(short8*)&lds[ky][px+1][cb] = Z8;
      }
    } else {
      size_t base0 = (size_t)(b*HH + ys)*WW*SPLIT;
      size_t base1 = (size_t)(b*HH + ys)*WW*(CIN-SPLIT);
      for(int c8 = tid; c8 < NCH; c8 += 256){
        int px = c8 / (CIN/8), cb = (c8 % (CIN/8))*8;
        short8 val;
        if(cb < SPLIT){
          val = *(const short8*)&in0[base0 + (size_t)px*SPLIT + cb];
        } else if constexpr (IN1F){
          const float* sp = &in1f[base1 + (size_t)px*(CIN-SPLIT) + cb - SPLIT];
          #pragma unroll
          for(int j=0;j<8;j++) val[j] = (short)f2bf(sp[j]);
        } else {
          val = *(const short8*)&in1b[base1 + (size_t)px*(CIN-SPLIT) + cb - SPLIT];
        }
        *(short8*)&lds[ky][px+1][cb] = val;
      }
    }
    for(int c8 = tid; c8 < 2*(CIN/8); c8 += 256){
      int which = c8 / (CIN/8); int cb = (c8 % (CIN/8))*8;
      *(short8*)&lds[ky][which ? (WW+1) : 0][cb] = Z8;
    }
  }
  __syncthreads();

  const f32x4 zf = {0.f,0.f,0.f,0.f};
  f32x4 acc[3][NTW];
  #pragma unroll
  for(int mt=0; mt<3; mt++)
    #pragma unroll
    for(int i=0; i<NTW; i++) acc[mt][i] = zf;

  #pragma unroll
  for(int ky=0; ky<3; ky++)
  #pragma unroll
  for(int kx=0; kx<3; kx++)
  #pragma unroll
  for(int ks=0; ks<CIN/32; ks++){
    short8 a[3];
    #pragma unroll
    for(int mt=0; mt<3; mt++)
      a[mt] = *(const short8*)&lds[ky][mt*16 + col + kx][ks*32 + g*8];
    #pragma unroll
    for(int i=0; i<NTW; i++){
      int co0 = (wave + 4*i)*16;
      const u16* wp = Wt + ((size_t)((ky*3+kx)*COUT) + co0 + col)*CIN + ks*32 + g*8;
      short8 bfr = *(const short8*)wp;
      #pragma unroll
      for(int mt=0; mt<3; mt++)
        acc[mt][i] = mfma16(a[mt], bfr, acc[mt][i]);
    }
  }

  if constexpr (!GATE){
    u16* out0 = (u16*)out0v;
    #pragma unroll
    for(int i=0; i<NTW; i++){
      int co = (wave + 4*i)*16 + col;
      float bs = bias[co];
      u16* op = out0 + (size_t)(b*HH + y)*WW*COUT + co;
      #pragma unroll
      for(int mt=0; mt<3; mt++)
        #pragma unroll
        for(int r=0; r<4; r++){
          int px = mt*16 + g*4 + r;
          op[(size_t)px*COUT] = f2bf(acc[mt][i][r] + bs);
        }
    }
  } else {
    float* oh = (float*)out0v;
    float* om = (float*)out1v;
    int c = wave*16 + col;
    float bo = bias[c], bg = bias[64+c], bgi = bias[128+c];
    #pragma unroll
    for(int mt=0; mt<3; mt++)
      #pragma unroll
      for(int r=0; r<4; r++){
        int px = mt*16 + g*4 + r;
        size_t idx = ((size_t)(b*HH + y)*WW + px)*64 + c;
        float mo = acc[mt][0][r] + bo;
        float mg = acc[mt][1][r] + bg;
        float gi = acc[mt][2][r] + bgi;
        float mval = mem[idx];
        float si = 1.f/(1.f + __expf(-gi));
        float nm = (1.f - si)*mval + si*tanhf(mg);
        float nh = (1.f/(1.f + __expf(-mo)))*nm;
        oh[idx] = nh;
        om[idx] = nm;
      }
  }
}

// ---------------- launcher ----------------
extern "C" void kernel_launch(void* const* d_in, const int* in_sizes, int n_in,
                              void* d_out, int out_size, void* d_ws, size_t ws_size,
                              hipStream_t stream){
  (void)in_sizes; (void)n_in; (void)out_size; (void)ws_size;
  const float* h   = (const float*)d_in[0];
  const float* m   = (const float*)d_in[1];
  const float* Wq  = (const float*)d_in[2];  const float* bq  = (const float*)d_in[3];
  const float* Wk  = (const float*)d_in[4];  const float* bk  = (const float*)d_in[5];
  const float* Wk2 = (const float*)d_in[6];  const float* bk2 = (const float*)d_in[7];
  const float* Wv  = (const float*)d_in[8];  const float* bv  = (const float*)d_in[9];
  const float* Wv2 = (const float*)d_in[10]; const float* bv2 = (const float*)d_in[11];
  const float* Wz  = (const float*)d_in[12]; const float* bz  = (const float*)d_in[13];
  const float* Wm  = (const float*)d_in[14]; const float* bm  = (const float*)d_in[15];

  const size_t NPIX = (size_t)BB*NSEQ*DD;  // 1,179,648

  u16* ws = (u16*)d_ws;
  u16* WtQ  = ws + 0;
  u16* WtK  = ws + 36864;
  u16* WtK2 = ws + 73728;
  u16* WtV  = ws + 110592;
  u16* WtV2 = ws + 147456;
  u16* WtZ  = ws + 184320;       // 147456
  u16* WtM  = ws + 331776;       // 331776 -> ends at 663552
  u16* slotA = ws + 663552;      // q;   later Z low half
  u16* slotB = slotA + NPIX;     // k_h; later Z high half
  u16* slotC = slotB + NPIX;     // v_h^T [b][d][seq]
  u16* slotD = slotC + NPIX;     // k_m
  u16* slotE = slotD + NPIX;     // v_m^T [b][d][seq]
  u16* Zb    = slotA;            // 2*NPIX spanning A+B

  float* outh = (float*)d_out;   // final new_h (f32)
  float* outm = outh + NPIX;     // final new_m (f32)
  u16* zh = (u16*)d_out;         // bf16 staging inside d_out (dead before final writes)
  u16* zm = zh + NPIX;

  wtrans_kernel<<<dim3(144), 256, 0, stream>>>(Wq,  WtQ,  64, 64);
  wtrans_kernel<<<dim3(144), 256, 0, stream>>>(Wk,  WtK,  64, 64);
  wtrans_kernel<<<dim3(144), 256, 0, stream>>>(Wk2, WtK2, 64, 64);
  wtrans_kernel<<<dim3(144), 256, 0, stream>>>(Wv,  WtV,  64, 64);
  wtrans_kernel<<<dim3(144), 256, 0, stream>>>(Wv2, WtV2, 64, 64);
  wtrans_kernel<<<dim3(288), 256, 0, stream>>>(Wz,  WtZ,  128, 128);
  wtrans_kernel<<<dim3(576), 256, 0, stream>>>(Wm,  WtM,  192, 192);

  ConvPtrs ph;
  ph.W[0]=WtQ;  ph.W[1]=WtK;  ph.W[2]=WtV;
  ph.bias[0]=bq; ph.bias[1]=bk; ph.bias[2]=bv;
  ph.out[0]=slotA; ph.out[1]=slotB; ph.out[2]=slotC;
  ph.vt[0]=0; ph.vt[1]=0; ph.vt[2]=1;
  conv64_mfma<3><<<dim3(BB*HH), 256, 0, stream>>>(h, ph);

  ConvPtrs pm;
  pm.W[0]=WtK2; pm.W[1]=WtV2; pm.W[2]=WtV2;
  pm.bias[0]=bk2; pm.bias[1]=bv2; pm.bias[2]=bv2;
  pm.out[0]=slotD; pm.out[1]=slotE; pm.out[2]=slotE;
  pm.vt[0]=0; pm.vt[1]=1; pm.vt[2]=1;
  conv64_mfma<2><<<dim3(BB*HH), 256, 0, stream>>>(m, pm);

  // fused dual attention (QBLK=32) -> z_h, z_m staged bf16 in d_out
  attn2_mfma<<<dim3(NSEQ/32, BB), 256, 0, stream>>>(
      slotA, slotB, slotC, slotD, slotE, zh, zm);

  // Z = conv(concat(z_h, z_m)) -> bf16 into Zb (q, k_h slots dead)
  bigconv_mfma<128,128,64,false,false><<<dim3(BB*HH), 256, 0, stream>>>(
      zh, zm, (const float*)0, WtZ, bz, (void*)Zb, (void*)0, (const float*)0);

  // combined = conv(concat(Z, h)); fused gating -> f32 outputs
  bigconv_mfma<192,192,128,true,true><<<dim3(BB*HH), 256, 0, stream>>>(
      Zb, (const u16*)0, h, WtM, bm, (void*)outh, (void*)outm, m);
}

// Round 10
// 258.808 us; speedup vs baseline: 11.4352x; 1.0187x over previous
//
#include <hip/hip_runtime.h>

#define BB 8
#define HH 48
#define WW 48
#define DD 64
#define NSEQ (HH*WW)   // 2304

typedef unsigned short u16;
typedef unsigned long long u64;
typedef __attribute__((ext_vector_type(8))) short short8;
typedef __attribute__((ext_vector_type(4))) float f32x4;

__device__ __forceinline__ float bf2f(u16 u){ return __uint_as_float(((unsigned)u)<<16); }
__device__ __forceinline__ u16 f2bf(float f){
  unsigned u = __float_as_uint(f);
  return (u16)((u + 0x7fffu + ((u>>16)&1u)) >> 16);   // RNE
}
__device__ __forceinline__ f32x4 mfma16(short8 a, short8 b, f32x4 c){
  return __builtin_amdgcn_mfma_f32_16x16x32_bf16(a, b, c, 0, 0, 0);
}

// ------- weight transpose: src f32 [9][CI][CO] -> dst bf16 [9][CO][CI] ----------------
__global__ void wtrans_kernel(const float* __restrict__ src, u16* __restrict__ dst,
                              int CI, int CO){
  int total = 9*CI*CO;
  for(int i = blockIdx.x*blockDim.x + threadIdx.x; i < total; i += gridDim.x*blockDim.x){
    int kk  = i / (CI*CO);
    int rem = i % (CI*CO);
    int co  = rem / CI;
    int ci  = rem % CI;
    dst[i] = f2bf(src[kk*CI*CO + ci*CO + co]);
  }
}

// ---------------- multi-conv 64->64 (MFMA); optional transposed [b][co][seq] output ----
struct ConvPtrs {
  const u16*   W[3];     // bf16 [9][co][ci]
  const float* bias[3];  // f32
  u16*         out[3];   // bf16
  int          vt[3];    // 1 -> write transposed [b][co][seq]
};

template<int NC>
__global__ __launch_bounds__(256) void conv64_mfma(const float* __restrict__ in, ConvPtrs p){
  const int SP = 72;
  __shared__ u16 lds[3][WW+2][SP];
  const int b = blockIdx.x / HH, y = blockIdx.x % HH;
  const int tid  = threadIdx.x;
  const int wave = tid >> 6, lane = tid & 63, g = lane >> 4, col = lane & 15;
  const short8 Z8 = {0,0,0,0,0,0,0,0};

  for(int ky=0; ky<3; ky++){
    int ys = y + ky - 1;
    const int NCH = WW*64/8;
    if(ys < 0 || ys >= HH){
      for(int c8 = tid; c8 < NCH; c8 += 256){
        int px = c8 >> 3, cb = (c8 & 7)*8;
        *(short8*)&lds[ky][px+1][cb] = Z8;
      }
    } else {
      const float* rowp = in + (size_t)(b*HH + ys)*WW*64;
      for(int c8 = tid; c8 < NCH; c8 += 256){
        int px = c8 >> 3, cb = (c8 & 7)*8;
        short8 v;
        #pragma unroll
        for(int j=0;j<8;j++) v[j] = (short)f2bf(rowp[px*64 + cb + j]);
        *(short8*)&lds[ky][px+1][cb] = v;
      }
    }
    for(int c8 = tid; c8 < 16; c8 += 256){
      int which = c8 >> 3; int cb = (c8 & 7)*8;
      *(short8*)&lds[ky][which ? (WW+1) : 0][cb] = Z8;
    }
  }
  __syncthreads();

  const f32x4 zf = {0.f,0.f,0.f,0.f};
  f32x4 acc[3][NC];
  #pragma unroll
  for(int mt=0; mt<3; mt++)
    #pragma unroll
    for(int c=0; c<NC; c++) acc[mt][c] = zf;

  #pragma unroll
  for(int ky=0; ky<3; ky++)
  #pragma unroll
  for(int kx=0; kx<3; kx++)
  #pragma unroll
  for(int ks=0; ks<2; ks++){
    short8 a[3];
    #pragma unroll
    for(int mt=0; mt<3; mt++)
      a[mt] = *(const short8*)&lds[ky][mt*16 + col + kx][ks*32 + g*8];
    #pragma unroll
    for(int c=0; c<NC; c++){
      const u16* wp = p.W[c] + ((size_t)((ky*3+kx)*64) + (wave*16 + col))*64 + ks*32 + g*8;
      short8 bfr = *(const short8*)wp;
      #pragma unroll
      for(int mt=0; mt<3; mt++)
        acc[mt][c] = mfma16(a[mt], bfr, acc[mt][c]);
    }
  }

  #pragma unroll
  for(int c=0; c<NC; c++){
    int co = wave*16 + col;
    float bs = p.bias[c][co];
    if(p.vt[c]){
      u16* op = p.out[c] + ((size_t)(b*64 + co))*NSEQ + (size_t)y*WW;
      #pragma unroll
      for(int mt=0; mt<3; mt++){
        int px = mt*16 + g*4;
        u64 pk =  (u64)f2bf(acc[mt][c][0] + bs)
               | ((u64)f2bf(acc[mt][c][1] + bs) << 16)
               | ((u64)f2bf(acc[mt][c][2] + bs) << 32)
               | ((u64)f2bf(acc[mt][c][3] + bs) << 48);
        *(u64*)&op[px] = pk;
      }
    } else {
      u16* op = p.out[c] + ((size_t)(b*HH + y)*WW)*64 + co;
      #pragma unroll
      for(int mt=0; mt<3; mt++)
        #pragma unroll
        for(int r=0; r<4; r++){
          int px = mt*16 + g*4 + r;
          op[(size_t)px*64] = f2bf(acc[mt][c][r] + bs);
        }
    }
  }
}

// ------- fused dual flash attention: QBLK=32, 4 waves (2 strips x 2 streams) ----------
// V inputs pre-transposed [b][d][seq]; K row-major [b][seq][d].
// LDS tiles are granule-XOR swizzled: elem(r,c) -> r*64 + ((c>>3)^(r&7))*8 + (c&7).
__global__ __launch_bounds__(256) void attn2_mfma(
    const u16* __restrict__ q,
    const u16* __restrict__ kh, const u16* __restrict__ vhT,
    const u16* __restrict__ km2, const u16* __restrict__ vmT,
    u16* __restrict__ zh, u16* __restrict__ zm){
  __shared__ u16 Ks [2*64*64];   // [stream][key][d] swizzled
  __shared__ u16 Vts[2*64*64];   // [stream][d][key] swizzled
  __shared__ u16 Ps [2*32*64];   // [stream][qrow][key] swizzled (wave-private strips)
  const int qt = blockIdx.x, b = blockIdx.y;
  const int tid = threadIdx.x, wave = tid>>6, lane = tid&63;
  const int g = lane>>4, col = lane&15;
  const int strip = wave & 1, s = wave >> 1;

  // Q fragments straight from global (row = qt*32 + strip*16 + col)
  const u16* qp = q + ((size_t)(b*NSEQ + qt*32 + strip*16 + col))*DD;
  short8 aq0 = *(const short8*)&qp[g*8];
  short8 aq1 = *(const short8*)&qp[32 + g*8];

  // staging: per tensor 512 short8-chunks; 256 threads -> 2 each
  const int r0a = tid>>3, gr = tid&7, cb0 = gr*8;
  const int r0b = r0a + 32;
  const int stA = r0a*64 + ((gr ^ (r0a&7))<<3);   // swizzled store offset, chunk A
  const int stB = stA + 32*64;                    // (r0b&7)==(r0a&7)
  const size_t tb  = (size_t)(b*NSEQ)*DD;
  const size_t tbT = (size_t)(b*64)*NSEQ;

  // swizzled read column offsets (constant per lane)
  const int cg0 = ((g     ^ (col&7))<<3);         // ks=0 granule
  const int cg1 = (((4+g) ^ (col&7))<<3);         // ks=1 granule

  short8 paK0,paK1,paV0,paV1,paKm0,paKm1,paVm0,paVm1;
  short8 pbK0,pbK1,pbV0,pbV1,pbKm0,pbKm1,pbVm0,pbVm1;

  const f32x4 zf = {0.f,0.f,0.f,0.f};
  f32x4 o[4];
  #pragma unroll
  for(int nt=0; nt<4; nt++) o[nt] = zf;
  float mst[4], lst[4];
  #pragma unroll
  for(int r=0; r<4; r++){ mst[r] = -1e30f; lst[r] = 0.f; }

#define BAR() { __builtin_amdgcn_s_barrier(); __builtin_amdgcn_sched_barrier(0); }
#define LWAIT() { asm volatile("s_waitcnt lgkmcnt(0)" ::: "memory"); __builtin_amdgcn_sched_barrier(0); }

#define LOADSET(K0,K1,V0,V1,Km0,Km1,Vm0,Vm1, kt_) {                        \
    size_t offK0 = tb + (size_t)(kt_)*64*DD + (size_t)r0a*DD + cb0;        \
    size_t offK1 = tb + (size_t)(kt_)*64*DD + (size_t)r0b*DD + cb0;        \
    size_t offV0 = tbT + (size_t)r0a*NSEQ + (size_t)(kt_)*64 + cb0;        \
    size_t offV1 = tbT + (size_t)r0b*NSEQ + (size_t)(kt_)*64 + cb0;        \
    K0  = *(const short8*)&kh [offK0];  K1  = *(const short8*)&kh [offK1]; \
    Km0 = *(const short8*)&km2[offK0];  Km1 = *(const short8*)&km2[offK1]; \
    V0  = *(const short8*)&vhT[offV0];  V1  = *(const short8*)&vhT[offV1]; \
    Vm0 = *(const short8*)&vmT[offV0];  Vm1 = *(const short8*)&vmT[offV1]; \
  }
#define STORESET(K0,K1,V0,V1,Km0,Km1,Vm0,Vm1) {                            \
    *(short8*)&Ks [stA]        = K0;   *(short8*)&Ks [stB]        = K1;    \
    *(short8*)&Ks [4096 + stA] = Km0;  *(short8*)&Ks [4096 + stB] = Km1;   \
    *(short8*)&Vts[stA]        = V0;   *(short8*)&Vts[stB]        = V1;    \
    *(short8*)&Vts[4096 + stA] = Vm0;  *(short8*)&Vts[4096 + stB] = Vm1;   \
  }
#define COMPUTE() {                                                 \
    __builtin_amdgcn_s_setprio(1);                                  \
    f32x4 sv[4];                                                    \
    _Pragma("unroll")                                               \
    for(int nt=0; nt<4; nt++){                                      \
      sv[nt] = zf;                                                  \
      int rowb = s*4096 + (nt*16 + col)*64;                         \
      short8 bk0 = *(const short8*)&Ks[rowb + cg0];                 \
      sv[nt] = mfma16(aq0, bk0, sv[nt]);                            \
      short8 bk1 = *(const short8*)&Ks[rowb + cg1];                 \
      sv[nt] = mfma16(aq1, bk1, sv[nt]);                            \
    }                                                               \
    _Pragma("unroll")                                               \
    for(int r=0; r<4; r++){                                         \
      float mx = fmaxf(fmaxf(sv[0][r], sv[1][r]), fmaxf(sv[2][r], sv[3][r])); \
      mx = fmaxf(mx, __shfl_xor(mx, 8));                            \
      mx = fmaxf(mx, __shfl_xor(mx, 4));                            \
      mx = fmaxf(mx, __shfl_xor(mx, 2));                            \
      mx = fmaxf(mx, __shfl_xor(mx, 1));                            \
      float mnew = fmaxf(mst[r], mx);                               \
      float scale = __expf(mst[r] - mnew);                          \
      mst[r] = mnew;                                                \
      lst[r] *= scale;                                              \
      _Pragma("unroll")                                             \
      for(int nt=0; nt<4; nt++) o[nt][r] *= scale;                  \
      float rs = 0.f;                                               \
      _Pragma("unroll")                                             \
      for(int nt=0; nt<4; nt++){                                    \
        float pv = __expf(sv[nt][r] - mnew);                        \
        sv[nt][r] = pv;                                             \
        rs += pv;                                                   \
      }                                                             \
      rs += __shfl_xor(rs, 8);                                      \
      rs += __shfl_xor(rs, 4);                                      \
      rs += __shfl_xor(rs, 2);                                      \
      rs += __shfl_xor(rs, 1);                                      \
      lst[r] += rs;                                                 \
      int prow = strip*16 + g*4 + r;                                \
      int pbase = s*2048 + prow*64;                                 \
      _Pragma("unroll")                                             \
      for(int nt=0; nt<4; nt++)                                     \
        Ps[pbase + (((nt*2 + (col>>3)) ^ (prow&7))<<3) + (col&7)] = f2bf(sv[nt][r]); \
    }                                                               \
    int prowr = strip*16 + col;                                     \
    _Pragma("unroll")                                               \
    for(int ks=0; ks<2; ks++){                                      \
      short8 ap = *(const short8*)&Ps[s*2048 + prowr*64 + (ks ? cg1 : cg0)]; \
      _Pragma("unroll")                                             \
      for(int nt=0; nt<4; nt++){                                    \
        short8 bv = *(const short8*)&Vts[s*4096 + (nt*16 + col)*64 + (ks ? cg1 : cg0)]; \
        o[nt] = mfma16(ap, bv, o[nt]);                              \
      }                                                             \
    }                                                               \
    __builtin_amdgcn_s_setprio(0);                                  \
  }

  LOADSET(paK0,paK1,paV0,paV1,paKm0,paKm1,paVm0,paVm1, 0);
  for(int kt = 0; kt < NSEQ/64; kt += 2){
    LOADSET(pbK0,pbK1,pbV0,pbV1,pbKm0,pbKm1,pbVm0,pbVm1, kt+1);
    BAR();                 // all waves done reading previous tile
    STORESET(paK0,paK1,paV0,paV1,paKm0,paKm1,paVm0,paVm1);
    LWAIT();               // publish ds_writes (prefetch loads stay in flight)
    BAR();
    COMPUTE();
    if(kt+2 < NSEQ/64) LOADSET(paK0,paK1,paV0,paV1,paKm0,paKm1,paVm0,paVm1, kt+2);
    BAR();
    STORESET(pbK0,pbK1,pbV0,pbV1,pbKm0,pbKm1,pbVm0,pbVm1);
    LWAIT();
    BAR();
    COMPUTE();
  }

  float inv[4];
  #pragma unroll
  for(int r=0; r<4; r++) inv[r] = 1.f/lst[r];
  u16* zout = s ? zm : zh;
  u16* zb = zout + ((size_t)(b*NSEQ + qt*32 + strip*16))*DD;
  #pragma unroll
  for(int nt=0; nt<4; nt++)
    #pragma unroll
    for(int r=0; r<4; r++)
      zb[(g*4 + r)*DD + nt*16 + col] = f2bf(o[nt][r]*inv[r]);
#undef LOADSET
#undef STORESET
#undef COMPUTE
#undef BAR
#undef LWAIT
}

// -------- big conv (MFMA, concat input): in0 bf16; in1 bf16 or f32; GATE -> f32 out ----
template<int CIN, int COUT, int SPLIT, bool GATE, bool IN1F>
__global__ __launch_bounds__(256) void bigconv_mfma(
    const u16* __restrict__ in0, const u16* __restrict__ in1b, const float* __restrict__ in1f,
    const u16* __restrict__ Wt, const float* __restrict__ bias,
    void* __restrict__ out0v, void* __restrict__ out1v, const float* __restrict__ mem){
  constexpr int SP  = CIN + 8;
  constexpr int NTW = COUT/64;
  __shared__ u16 lds[3][WW+2][SP];
  const int b = blockIdx.x / HH, y = blockIdx.x % HH;
  const int tid  = threadIdx.x;
  const int wave = tid >> 6, lane = tid & 63, g = lane >> 4, col = lane & 15;
  const short8 Z8 = {0,0,0,0,0,0,0,0};

  for(int ky=0; ky<3; ky++){
    int ys = y + ky - 1;
    const int NCH = WW*CIN/8;
    if(ys < 0 || ys >= HH){
      for(int c8 = tid; c8 < NCH; c8 += 256){
        int px = c8 / (CIN/8), cb = (c8 % (CIN/8))*8;
        *(short8*)&lds[ky][px+1][cb] = Z8;
      }
    } else {
      size_t base0 = (size_t)(b*HH + ys)*WW*SPLIT;
      size_t base1 = (size_t)(b*HH + ys)*WW*(CIN-SPLIT);
      for(int c8 = tid; c8 < NCH; c8 += 256){
        int px = c8 / (CIN/8), cb = (c8 % (CIN/8))*8;
        short8 val;
        if(cb < SPLIT){
          val = *(const short8*)&in0[base0 + (size_t)px*SPLIT + cb];
        } else if constexpr (IN1F){
          const float* sp = &in1f[base1 + (size_t)px*(CIN-SPLIT) + cb - SPLIT];
          #pragma unroll
          for(int j=0;j<8;j++) val[j] = (short)f2bf(sp[j]);
        } else {
          val = *(const short8*)&in1b[base1 + (size_t)px*(CIN-SPLIT) + cb - SPLIT];
        }
        *(short8*)&lds[ky][px+1][cb] = val;
      }
    }
    for(int c8 = tid; c8 < 2*(CIN/8); c8 += 256){
      int which = c8 / (CIN/8); int cb = (c8 % (CIN/8))*8;
      *(short8*)&lds[ky][which ? (WW+1) : 0][cb] = Z8;
    }
  }
  __syncthreads();

  const f32x4 zf = {0.f,0.f,0.f,0.f};
  f32x4 acc[3][NTW];
  #pragma unroll
  for(int mt=0; mt<3; mt++)
    #pragma unroll
    for(int i=0; i<NTW; i++) acc[mt][i] = zf;

  #pragma unroll
  for(int ky=0; ky<3; ky++)
  #pragma unroll
  for(int kx=0; kx<3; kx++)
  #pragma unroll
  for(int ks=0; ks<CIN/32; ks++){
    short8 a[3];
    #pragma unroll
    for(int mt=0; mt<3; mt++)
      a[mt] = *(const short8*)&lds[ky][mt*16 + col + kx][ks*32 + g*8];
    #pragma unroll
    for(int i=0; i<NTW; i++){
      int co0 = (wave + 4*i)*16;
      const u16* wp = Wt + ((size_t)((ky*3+kx)*COUT) + co0 + col)*CIN + ks*32 + g*8;
      short8 bfr = *(const short8*)wp;
      #pragma unroll
      for(int mt=0; mt<3; mt++)
        acc[mt][i] = mfma16(a[mt], bfr, acc[mt][i]);
    }
  }

  if constexpr (!GATE){
    u16* out0 = (u16*)out0v;
    #pragma unroll
    for(int i=0; i<NTW; i++){
      int co = (wave + 4*i)*16 + col;
      float bs = bias[co];
      u16* op = out0 + (size_t)(b*HH + y)*WW*COUT + co;
      #pragma unroll
      for(int mt=0; mt<3; mt++)
        #pragma unroll
        for(int r=0; r<4; r++){
          int px = mt*16 + g*4 + r;
          op[(size_t)px*COUT] = f2bf(acc[mt][i][r] + bs);
        }
    }
  } else {
    float* oh = (float*)out0v;
    float* om = (float*)out1v;
    int c = wave*16 + col;
    float bo = bias[c], bg = bias[64+c], bgi = bias[128+c];
    #pragma unroll
    for(int mt=0; mt<3; mt++)
      #pragma unroll
      for(int r=0; r<4; r++){
        int px = mt*16 + g*4 + r;
        size_t idx = ((size_t)(b*HH + y)*WW + px)*64 + c;
        float mo = acc[mt][0][r] + bo;
        float mg = acc[mt][1][r] + bg;
        float gi = acc[mt][2][r] + bgi;
        float mval = mem[idx];
        float si = 1.f/(1.f + __expf(-gi));
        float nm = (1.f - si)*mval + si*tanhf(mg);
        float nh = (1.f/(1.f + __expf(-mo)))*nm;
        oh[idx] = nh;
        om[idx] = nm;
      }
  }
}

// ---------------- launcher ----------------
extern "C" void kernel_launch(void* const* d_in, const int* in_sizes, int n_in,
                              void* d_out, int out_size, void* d_ws, size_t ws_size,
                              hipStream_t stream){
  (void)in_sizes; (void)n_in; (void)out_size; (void)ws_size;
  const float* h   = (const float*)d_in[0];
  const float* m   = (const float*)d_in[1];
  const float* Wq  = (const float*)d_in[2];  const float* bq  = (const float*)d_in[3];
  const float* Wk  = (const float*)d_in[4];  const float* bk  = (const float*)d_in[5];
  const float* Wk2 = (const float*)d_in[6];  const float* bk2 = (const float*)d_in[7];
  const float* Wv  = (const float*)d_in[8];  const float* bv  = (const float*)d_in[9];
  const float* Wv2 = (const float*)d_in[10]; const float* bv2 = (const float*)d_in[11];
  const float* Wz  = (const float*)d_in[12]; const float* bz  = (const float*)d_in[13];
  const float* Wm  = (const float*)d_in[14]; const float* bm  = (const float*)d_in[15];

  const size_t NPIX = (size_t)BB*NSEQ*DD;  // 1,179,648

  u16* ws = (u16*)d_ws;
  u16* WtQ  = ws + 0;
  u16* WtK  = ws + 36864;
  u16* WtK2 = ws + 73728;
  u16* WtV  = ws + 110592;
  u16* WtV2 = ws + 147456;
  u16* WtZ  = ws + 184320;       // 147456
  u16* WtM  = ws + 331776;       // 331776 -> ends at 663552
  u16* slotA = ws + 663552;      // q;   later Z low half
  u16* slotB = slotA + NPIX;     // k_h; later Z high half
  u16* slotC = slotB + NPIX;     // v_h^T [b][d][seq]
  u16* slotD = slotC + NPIX;     // k_m
  u16* slotE = slotD + NPIX;     // v_m^T [b][d][seq]
  u16* Zb    = slotA;            // 2*NPIX spanning A+B

  float* outh = (float*)d_out;   // final new_h (f32)
  float* outm = outh + NPIX;     // final new_m (f32)
  u16* zh = (u16*)d_out;         // bf16 staging inside d_out (dead before final writes)
  u16* zm = zh + NPIX;

  wtrans_kernel<<<dim3(144), 256, 0, stream>>>(Wq,  WtQ,  64, 64);
  wtrans_kernel<<<dim3(144), 256, 0, stream>>>(Wk,  WtK,  64, 64);
  wtrans_kernel<<<dim3(144), 256, 0, stream>>>(Wk2, WtK2, 64, 64);
  wtrans_kernel<<<dim3(144), 256, 0, stream>>>(Wv,  WtV,  64, 64);
  wtrans_kernel<<<dim3(144), 256, 0, stream>>>(Wv2, WtV2, 64, 64);
  wtrans_kernel<<<dim3(288), 256, 0, stream>>>(Wz,  WtZ,  128, 128);
  wtrans_kernel<<<dim3(576), 256, 0, stream>>>(Wm,  WtM,  192, 192);

  ConvPtrs ph;
  ph.W[0]=WtQ;  ph.W[1]=WtK;  ph.W[2]=WtV;
  ph.bias[0]=bq; ph.bias[1]=bk; ph.bias[2]=bv;
  ph.out[0]=slotA; ph.out[1]=slotB; ph.out[2]=slotC;
  ph.vt[0]=0; ph.vt[1]=0; ph.vt[2]=1;
  conv64_mfma<3><<<dim3(BB*HH), 256, 0, stream>>>(h, ph);

  ConvPtrs pm;
  pm.W[0]=WtK2; pm.W[1]=WtV2; pm.W[2]=WtV2;
  pm.bias[0]=bk2; pm.bias[1]=bv2; pm.bias[2]=bv2;
  pm.out[0]=slotD; pm.out[1]=slotE; pm.out[2]=slotE;
  pm.vt[0]=0; pm.vt[1]=1; pm.vt[2]=1;
  conv64_mfma<2><<<dim3(BB*HH), 256, 0, stream>>>(m, pm);

  // fused dual attention (QBLK=32) -> z_h, z_m staged bf16 in d_out
  attn2_mfma<<<dim3(NSEQ/32, BB), 256, 0, stream>>>(
      slotA, slotB, slotC, slotD, slotE, zh, zm);

  // Z = conv(concat(z_h, z_m)) -> bf16 into Zb (q, k_h slots dead)
  bigconv_mfma<128,128,64,false,false><<<dim3(BB*HH), 256, 0, stream>>>(
      zh, zm, (const float*)0, WtZ, bz, (void*)Zb, (void*)0, (const float*)0);

  // combined = conv(concat(Z, h)); fused gating -> f32 outputs
  bigconv_mfma<192,192,128,true,true><<<dim3(BB*HH), 256, 0, stream>>>(
      Zb, (const u16*)0, h, WtM, bm, (void*)outh, (void*)outm, m);
}

// Round 11
// 221.724 us; speedup vs baseline: 13.3478x; 1.1673x over previous
//
#include <hip/hip_runtime.h>

#define BB 8
#define HH 48
#define WW 48
#define DD 64
#define NSEQ (HH*WW)   // 2304

typedef unsigned short u16;
typedef unsigned long long u64;
typedef __attribute__((ext_vector_type(8))) short short8;
typedef __attribute__((ext_vector_type(4))) float f32x4;

__device__ __forceinline__ float bf2f(u16 u){ return __uint_as_float(((unsigned)u)<<16); }
__device__ __forceinline__ u16 f2bf(float f){
  unsigned u = __float_as_uint(f);
  return (u16)((u + 0x7fffu + ((u>>16)&1u)) >> 16);   // RNE
}
__device__ __forceinline__ f32x4 mfma16(short8 a, short8 b, f32x4 c){
  return __builtin_amdgcn_mfma_f32_16x16x32_bf16(a, b, c, 0, 0, 0);
}

// ------- fused weight transpose: all 7 tensors, [9][CI][CO] f32 -> [9][CO][CI] bf16 ----
struct WtSrcs { const float* src[7]; };
__global__ __launch_bounds__(256) void wtrans_all(WtSrcs s, u16* __restrict__ dst){
  int i = blockIdx.x*256 + threadIdx.x;       // total 663552
  if(i >= 663552) return;
  const float* sp; int local, CI;
  if(i < 184320){ int seg = i/36864; local = i - seg*36864; sp = s.src[seg]; CI = 64; }
  else if(i < 331776){ local = i - 184320; sp = s.src[5]; CI = 128; }
  else { local = i - 331776; sp = s.src[6]; CI = 192; }
  int per = CI*CI;
  int kk = local / per, rem = local % per;
  int co = rem / CI, ci = rem % CI;
  dst[i] = f2bf(sp[kk*per + ci*CI + co]);
}

// ---------------- multi-conv 64->64 (MFMA); optional transposed [b][co][seq] output ----
struct ConvPtrs {
  const u16*   W[3];     // bf16 [9][co][ci]
  const float* bias[3];  // f32
  u16*         out[3];   // bf16
  int          vt[3];    // 1 -> write transposed [b][co][seq]
};

template<int NC>
__global__ __launch_bounds__(256) void conv64_mfma(const float* __restrict__ in, ConvPtrs p){
  const int SP = 72;
  __shared__ u16 lds[3][WW+2][SP];
  const int b = blockIdx.x / HH, y = blockIdx.x % HH;
  const int tid  = threadIdx.x;
  const int wave = tid >> 6, lane = tid & 63, g = lane >> 4, col = lane & 15;
  const short8 Z8 = {0,0,0,0,0,0,0,0};

  for(int ky=0; ky<3; ky++){
    int ys = y + ky - 1;
    const int NCH = WW*64/8;
    if(ys < 0 || ys >= HH){
      for(int c8 = tid; c8 < NCH; c8 += 256){
        int px = c8 >> 3, cb = (c8 & 7)*8;
        *(short8*)&lds[ky][px+1][cb] = Z8;
      }
    } else {
      const float* rowp = in + (size_t)(b*HH + ys)*WW*64;
      for(int c8 = tid; c8 < NCH; c8 += 256){
        int px = c8 >> 3, cb = (c8 & 7)*8;
        short8 v;
        #pragma unroll
        for(int j=0;j<8;j++) v[j] = (short)f2bf(rowp[px*64 + cb + j]);
        *(short8*)&lds[ky][px+1][cb] = v;
      }
    }
    for(int c8 = tid; c8 < 16; c8 += 256){
      int which = c8 >> 3; int cb = (c8 & 7)*8;
      *(short8*)&lds[ky][which ? (WW+1) : 0][cb] = Z8;
    }
  }
  __syncthreads();

  const f32x4 zf = {0.f,0.f,0.f,0.f};
  f32x4 acc[3][NC];
  #pragma unroll
  for(int mt=0; mt<3; mt++)
    #pragma unroll
    for(int c=0; c<NC; c++) acc[mt][c] = zf;

  #pragma unroll
  for(int ky=0; ky<3; ky++)
  #pragma unroll
  for(int kx=0; kx<3; kx++)
  #pragma unroll
  for(int ks=0; ks<2; ks++){
    short8 a[3];
    #pragma unroll
    for(int mt=0; mt<3; mt++)
      a[mt] = *(const short8*)&lds[ky][mt*16 + col + kx][ks*32 + g*8];
    #pragma unroll
    for(int c=0; c<NC; c++){
      const u16* wp = p.W[c] + ((size_t)((ky*3+kx)*64) + (wave*16 + col))*64 + ks*32 + g*8;
      short8 bfr = *(const short8*)wp;
      #pragma unroll
      for(int mt=0; mt<3; mt++)
        acc[mt][c] = mfma16(a[mt], bfr, acc[mt][c]);
    }
  }

  #pragma unroll
  for(int c=0; c<NC; c++){
    int co = wave*16 + col;
    float bs = p.bias[c][co];
    if(p.vt[c]){
      u16* op = p.out[c] + ((size_t)(b*64 + co))*NSEQ + (size_t)y*WW;
      #pragma unroll
      for(int mt=0; mt<3; mt++){
        int px = mt*16 + g*4;
        u64 pk =  (u64)f2bf(acc[mt][c][0] + bs)
               | ((u64)f2bf(acc[mt][c][1] + bs) << 16)
               | ((u64)f2bf(acc[mt][c][2] + bs) << 32)
               | ((u64)f2bf(acc[mt][c][3] + bs) << 48);
        *(u64*)&op[px] = pk;
      }
    } else {
      u16* op = p.out[c] + ((size_t)(b*HH + y)*WW)*64 + co;
      #pragma unroll
      for(int mt=0; mt<3; mt++)
        #pragma unroll
        for(int r=0; r<4; r++){
          int px = mt*16 + g*4 + r;
          op[(size_t)px*64] = f2bf(acc[mt][c][r] + bs);
        }
    }
  }
}

// ------- split-K fused dual flash attention: QBLK=32, KV split in 2 chunks -----------
// blockIdx.z = chunk. Emits UNNORMALIZED partial O (bf16) + per-row (m,l).
// po regions (u16): [h-c0][h-c1][m-c0][m-c1], each NPIX.
__global__ __launch_bounds__(256) void attn2_mfma(
    const u16* __restrict__ q,
    const u16* __restrict__ kh, const u16* __restrict__ vhT,
    const u16* __restrict__ km2, const u16* __restrict__ vmT,
    u16* __restrict__ po, float2* __restrict__ ml){
  __shared__ u16 Ks [2*64*64];   // [stream][key][d] swizzled
  __shared__ u16 Vts[2*64*64];   // [stream][d][key] swizzled
  __shared__ u16 Ps [2*32*64];   // [stream][qrow][key] swizzled (wave-private strips)
  const int qt = blockIdx.x, b = blockIdx.y, ch = blockIdx.z;
  const int tid = threadIdx.x, wave = tid>>6, lane = tid&63;
  const int g = lane>>4, col = lane&15;
  const int strip = wave & 1, s = wave >> 1;
  const size_t NP = (size_t)BB*NSEQ*DD;

  const u16* qp = q + ((size_t)(b*NSEQ + qt*32 + strip*16 + col))*DD;
  short8 aq0 = *(const short8*)&qp[g*8];
  short8 aq1 = *(const short8*)&qp[32 + g*8];

  const int r0a = tid>>3, gr = tid&7, cb0 = gr*8;
  const int r0b = r0a + 32;
  const int stA = r0a*64 + ((gr ^ (r0a&7))<<3);
  const int stB = stA + 32*64;
  const size_t tb  = (size_t)(b*NSEQ)*DD;
  const size_t tbT = (size_t)(b*64)*NSEQ;

  const int cg0 = ((g     ^ (col&7))<<3);
  const int cg1 = (((4+g) ^ (col&7))<<3);

  short8 paK0,paK1,paV0,paV1,paKm0,paKm1,paVm0,paVm1;
  short8 pbK0,pbK1,pbV0,pbV1,pbKm0,pbKm1,pbVm0,pbVm1;

  const f32x4 zf = {0.f,0.f,0.f,0.f};
  f32x4 o[4];
  #pragma unroll
  for(int nt=0; nt<4; nt++) o[nt] = zf;
  float mst[4], lst[4];
  #pragma unroll
  for(int r=0; r<4; r++){ mst[r] = -1e30f; lst[r] = 0.f; }

#define BAR() { __builtin_amdgcn_s_barrier(); __builtin_amdgcn_sched_barrier(0); }
#define LWAIT() { asm volatile("s_waitcnt lgkmcnt(0)" ::: "memory"); __builtin_amdgcn_sched_barrier(0); }

#define LOADSET(K0,K1,V0,V1,Km0,Km1,Vm0,Vm1, kt_) {                        \
    size_t offK0 = tb + (size_t)(kt_)*64*DD + (size_t)r0a*DD + cb0;        \
    size_t offK1 = tb + (size_t)(kt_)*64*DD + (size_t)r0b*DD + cb0;        \
    size_t offV0 = tbT + (size_t)r0a*NSEQ + (size_t)(kt_)*64 + cb0;        \
    size_t offV1 = tbT + (size_t)r0b*NSEQ + (size_t)(kt_)*64 + cb0;        \
    K0  = *(const short8*)&kh [offK0];  K1  = *(const short8*)&kh [offK1]; \
    Km0 = *(const short8*)&km2[offK0];  Km1 = *(const short8*)&km2[offK1]; \
    V0  = *(const short8*)&vhT[offV0];  V1  = *(const short8*)&vhT[offV1]; \
    Vm0 = *(const short8*)&vmT[offV0];  Vm1 = *(const short8*)&vmT[offV1]; \
  }
#define STORESET(K0,K1,V0,V1,Km0,Km1,Vm0,Vm1) {                            \
    *(short8*)&Ks [stA]        = K0;   *(short8*)&Ks [stB]        = K1;    \
    *(short8*)&Ks [4096 + stA] = Km0;  *(short8*)&Ks [4096 + stB] = Km1;   \
    *(short8*)&Vts[stA]        = V0;   *(short8*)&Vts[stB]        = V1;    \
    *(short8*)&Vts[4096 + stA] = Vm0;  *(short8*)&Vts[4096 + stB] = Vm1;   \
  }
#define COMPUTE() {                                                 \
    __builtin_amdgcn_s_setprio(1);                                  \
    f32x4 sv[4];                                                    \
    _Pragma("unroll")                                               \
    for(int nt=0; nt<4; nt++){                                      \
      sv[nt] = zf;                                                  \
      int rowb = s*4096 + (nt*16 + col)*64;                         \
      short8 bk0 = *(const short8*)&Ks[rowb + cg0];                 \
      sv[nt] = mfma16(aq0, bk0, sv[nt]);                            \
      short8 bk1 = *(const short8*)&Ks[rowb + cg1];                 \
      sv[nt] = mfma16(aq1, bk1, sv[nt]);                            \
    }                                                               \
    _Pragma("unroll")                                               \
    for(int r=0; r<4; r++){                                         \
      float mx = fmaxf(fmaxf(sv[0][r], sv[1][r]), fmaxf(sv[2][r], sv[3][r])); \
      mx = fmaxf(mx, __shfl_xor(mx, 8));                            \
      mx = fmaxf(mx, __shfl_xor(mx, 4));                            \
      mx = fmaxf(mx, __shfl_xor(mx, 2));                            \
      mx = fmaxf(mx, __shfl_xor(mx, 1));                            \
      float mnew = fmaxf(mst[r], mx);                               \
      float scale = __expf(mst[r] - mnew);                          \
      mst[r] = mnew;                                                \
      lst[r] *= scale;                                              \
      _Pragma("unroll")                                             \
      for(int nt=0; nt<4; nt++) o[nt][r] *= scale;                  \
      float rs = 0.f;                                               \
      _Pragma("unroll")                                             \
      for(int nt=0; nt<4; nt++){                                    \
        float pv = __expf(sv[nt][r] - mnew);                        \
        sv[nt][r] = pv;                                             \
        rs += pv;                                                   \
      }                                                             \
      rs += __shfl_xor(rs, 8);                                      \
      rs += __shfl_xor(rs, 4);                                      \
      rs += __shfl_xor(rs, 2);                                      \
      rs += __shfl_xor(rs, 1);                                      \
      lst[r] += rs;                                                 \
      int prow = strip*16 + g*4 + r;                                \
      int pbase = s*2048 + prow*64;                                 \
      _Pragma("unroll")                                             \
      for(int nt=0; nt<4; nt++)                                     \
        Ps[pbase + (((nt*2 + (col>>3)) ^ (prow&7))<<3) + (col&7)] = f2bf(sv[nt][r]); \
    }                                                               \
    int prowr = strip*16 + col;                                     \
    _Pragma("unroll")                                               \
    for(int ks=0; ks<2; ks++){                                      \
      short8 ap = *(const short8*)&Ps[s*2048 + prowr*64 + (ks ? cg1 : cg0)]; \
      _Pragma("unroll")                                             \
      for(int nt=0; nt<4; nt++){                                    \
        short8 bv = *(const short8*)&Vts[s*4096 + (nt*16 + col)*64 + (ks ? cg1 : cg0)]; \
        o[nt] = mfma16(ap, bv, o[nt]);                              \
      }                                                             \
    }                                                               \
    __builtin_amdgcn_s_setprio(0);                                  \
  }

  const int kt0 = ch*18;                     // 18 tiles of 64 keys per chunk
  LOADSET(paK0,paK1,paV0,paV1,paKm0,paKm1,paVm0,paVm1, kt0);
  for(int kt = kt0; kt < kt0+18; kt += 2){
    LOADSET(pbK0,pbK1,pbV0,pbV1,pbKm0,pbKm1,pbVm0,pbVm1, kt+1);
    BAR();
    STORESET(paK0,paK1,paV0,paV1,paKm0,paKm1,paVm0,paVm1);
    LWAIT();
    BAR();
    COMPUTE();
    if(kt+2 < kt0+18) LOADSET(paK0,paK1,paV0,paV1,paKm0,paKm1,paVm0,paVm1, kt+2);
    BAR();
    STORESET(pbK0,pbK1,pbV0,pbV1,pbKm0,pbKm1,pbVm0,pbVm1);
    LWAIT();
    BAR();
    COMPUTE();
  }

  // unnormalized partial O + (m,l)
  u16* pb = po + (size_t)(s*2 + ch)*NP + ((size_t)(b*NSEQ + qt*32 + strip*16))*DD;
  #pragma unroll
  for(int nt=0; nt<4; nt++)
    #pragma unroll
    for(int r=0; r<4; r++)
      pb[(g*4 + r)*DD + nt*16 + col] = f2bf(o[nt][r]);
  if(col == 0){
    #pragma unroll
    for(int r=0; r<4; r++){
      int qrow = qt*32 + strip*16 + g*4 + r;
      float2 v; v.x = mst[r]; v.y = lst[r];
      ml[(size_t)(s*2 + ch)*BB*NSEQ + (size_t)b*NSEQ + qrow] = v;
    }
  }
#undef LOADSET
#undef STORESET
#undef COMPUTE
#undef BAR
#undef LWAIT
}

// ------- combine 2 KV-chunks: in-place into po regions 0 (z_h) and 1 (z_m) -----------
__global__ __launch_bounds__(256) void attn_combine(u16* po, const float2* ml){
  const size_t NP = (size_t)BB*NSEQ*DD;
  const size_t RORD = (size_t)BB*NSEQ;
  for(size_t e = (size_t)blockIdx.x*256 + threadIdx.x; e < NP; e += (size_t)gridDim.x*256){
    size_t row = e / DD;
    float2 h0 = ml[row],         h1 = ml[RORD + row];
    float2 m0 = ml[2*RORD + row], m1 = ml[3*RORD + row];
    float oh0 = bf2f(po[e]),      oh1 = bf2f(po[NP + e]);
    float om0 = bf2f(po[2*NP + e]), om1 = bf2f(po[3*NP + e]);
    float M  = fmaxf(h0.x, h1.x);
    float a0 = __expf(h0.x - M), a1 = __expf(h1.x - M);
    float vh = (a0*oh0 + a1*oh1) / (a0*h0.y + a1*h1.y);
    M  = fmaxf(m0.x, m1.x);
    a0 = __expf(m0.x - M); a1 = __expf(m1.x - M);
    float vm = (a0*om0 + a1*om1) / (a0*m0.y + a1*m1.y);
    po[e]      = f2bf(vh);     // z_h
    po[NP + e] = f2bf(vm);     // z_m (overwrites h-c1, read by this thread only)
  }
}

// -------- big conv (MFMA, concat input): in0 bf16; in1 bf16 or f32; GATE -> f32 out ----
template<int CIN, int COUT, int SPLIT, bool GATE, bool IN1F>
__global__ __launch_bounds__(256) void bigconv_mfma(
    const u16* __restrict__ in0, const u16* __restrict__ in1b, const float* __restrict__ in1f,
    const u16* __restrict__ Wt, const float* __restrict__ bias,
    void* __restrict__ out0v, void* __restrict__ out1v, const float* __restrict__ mem){
  constexpr int SP  = CIN + 8;
  constexpr int NTW = COUT/64;
  __shared__ u16 lds[3][WW+2][SP];
  const int b = blockIdx.x / HH, y = blockIdx.x % HH;
  const int tid  = threadIdx.x;
  const int wave = tid >> 6, lane = tid & 63, g = lane >> 4, col = lane & 15;
  const short8 Z8 = {0,0,0,0,0,0,0,0};

  for(int ky=0; ky<3; ky++){
    int ys = y + ky - 1;
    const int NCH = WW*CIN/8;
    if(ys < 0 || ys >= HH){
      for(int c8 = tid; c8 < NCH; c8 += 256){
        int px = c8 / (CIN/8), cb = (c8 % (CIN/8))*8;
        *(short8*)&lds[ky][px+1][cb] = Z8;
      }
    } else {
      size_t base0 = (size_t)(b*HH + ys)*WW*SPLIT;
      size_t base1 = (size_t)(b*HH + ys)*WW*(CIN-SPLIT);
      for(int c8 = tid; c8 < NCH; c8 += 256){
        int px = c8 / (CIN/8), cb = (c8 % (CIN/8))*8;
        short8 val;
        if(cb < SPLIT){
          val = *(const short8*)&in0[base0 + (size_t)px*SPLIT + cb];
        } else if constexpr (IN1F){
          const float* sp = &in1f[base1 + (size_t)px*(CIN-SPLIT) + cb - SPLIT];
          #pragma unroll
          for(int j=0;j<8;j++) val[j] = (short)f2bf(sp[j]);
        } else {
          val = *(const short8*)&in1b[base1 + (size_t)px*(CIN-SPLIT) + cb - SPLIT];
        }
        *(short8*)&lds[ky][px+1][cb] = val;
      }
    }
    for(int c8 = tid; c8 < 2*(CIN/8); c8 += 256){
      int which = c8 / (CIN/8); int cb = (c8 % (CIN/8))*8;
      *(short8*)&lds[ky][which ? (WW+1) : 0][cb] = Z8;
    }
  }
  __syncthreads();

  const f32x4 zf = {0.f,0.f,0.f,0.f};
  f32x4 acc[3][NTW];
  #pragma unroll
  for(int mt=0; mt<3; mt++)
    #pragma unroll
    for(int i=0; i<NTW; i++) acc[mt][i] = zf;

  #pragma unroll
  for(int ky=0; ky<3; ky++)
  #pragma unroll
  for(int kx=0; kx<3; kx++)
  #pragma unroll
  for(int ks=0; ks<CIN/32; ks++){
    short8 a[3];
    #pragma unroll
    for(int mt=0; mt<3; mt++)
      a[mt] = *(const short8*)&lds[ky][mt*16 + col + kx][ks*32 + g*8];
    #pragma unroll
    for(int i=0; i<NTW; i++){
      int co0 = (wave + 4*i)*16;
      const u16* wp = Wt + ((size_t)((ky*3+kx)*COUT) + co0 + col)*CIN + ks*32 + g*8;
      short8 bfr = *(const short8*)wp;
      #pragma unroll
      for(int mt=0; mt<3; mt++)
        acc[mt][i] = mfma16(a[mt], bfr, acc[mt][i]);
    }
  }

  if constexpr (!GATE){
    u16* out0 = (u16*)out0v;
    #pragma unroll
    for(int i=0; i<NTW; i++){
      int co = (wave + 4*i)*16 + col;
      float bs = bias[co];
      u16* op = out0 + (size_t)(b*HH + y)*WW*COUT + co;
      #pragma unroll
      for(int mt=0; mt<3; mt++)
        #pragma unroll
        for(int r=0; r<4; r++){
          int px = mt*16 + g*4 + r;
          op[(size_t)px*COUT] = f2bf(acc[mt][i][r] + bs);
        }
    }
  } else {
    float* oh = (float*)out0v;
    float* om = (float*)out1v;
    int c = wave*16 + col;
    float bo = bias[c], bg = bias[64+c], bgi = bias[128+c];
    #pragma unroll
    for(int mt=0; mt<3; mt++)
      #pragma unroll
      for(int r=0; r<4; r++){
        int px = mt*16 + g*4 + r;
        size_t idx = ((size_t)(b*HH + y)*WW + px)*64 + c;
        float mo = acc[mt][0][r] + bo;
        float mg = acc[mt][1][r] + bg;
        float gi = acc[mt][2][r] + bgi;
        float mval = mem[idx];
        float si = 1.f/(1.f + __expf(-gi));
        float nm = (1.f - si)*mval + si*tanhf(mg);
        float nh = (1.f/(1.f + __expf(-mo)))*nm;
        oh[idx] = nh;
        om[idx] = nm;
      }
  }
}

// ---------------- launcher ----------------
extern "C" void kernel_launch(void* const* d_in, const int* in_sizes, int n_in,
                              void* d_out, int out_size, void* d_ws, size_t ws_size,
                              hipStream_t stream){
  (void)in_sizes; (void)n_in; (void)out_size; (void)ws_size;
  const float* h   = (const float*)d_in[0];
  const float* m   = (const float*)d_in[1];
  const float* Wq  = (const float*)d_in[2];  const float* bq  = (const float*)d_in[3];
  const float* Wk  = (const float*)d_in[4];  const float* bk  = (const float*)d_in[5];
  const float* Wk2 = (const float*)d_in[6];  const float* bk2 = (const float*)d_in[7];
  const float* Wv  = (const float*)d_in[8];  const float* bv  = (const float*)d_in[9];
  const float* Wv2 = (const float*)d_in[10]; const float* bv2 = (const float*)d_in[11];
  const float* Wz  = (const float*)d_in[12]; const float* bz  = (const float*)d_in[13];
  const float* Wm  = (const float*)d_in[14]; const float* bm  = (const float*)d_in[15];

  const size_t NPIX = (size_t)BB*NSEQ*DD;  // 1,179,648

  u16* ws = (u16*)d_ws;
  u16* WtQ  = ws + 0;            // all 7 transposed weights contiguous: 663552 u16
  u16* WtK  = ws + 36864;
  u16* WtK2 = ws + 73728;
  u16* WtV  = ws + 110592;
  u16* WtV2 = ws + 147456;
  u16* WtZ  = ws + 184320;
  u16* WtM  = ws + 331776;
  u16* slotA = ws + 663552;      // q;   later Z low half
  u16* slotB = slotA + NPIX;     // k_h; later Z high half
  u16* slotC = slotB + NPIX;     // v_h^T [b][d][seq]
  u16* slotD = slotC + NPIX;     // k_m
  u16* slotE = slotD + NPIX;     // v_m^T [b][d][seq]
  float2* ml = (float2*)(ws + 663552 + 5*NPIX);   // 4*BB*NSEQ float2 = 590 KB
  u16* Zb    = slotA;            // 2*NPIX spanning A+B

  float* outh = (float*)d_out;   // final new_h (f32)
  float* outm = outh + NPIX;     // final new_m (f32)
  u16* po = (u16*)d_out;         // partial-O regions [h-c0][h-c1][m-c0][m-c1], 4*NPIX u16
  u16* zh = po;                  // after combine: z_h
  u16* zm = po + NPIX;           // after combine: z_m

  WtSrcs wsrc;
  wsrc.src[0]=Wq; wsrc.src[1]=Wk; wsrc.src[2]=Wk2; wsrc.src[3]=Wv; wsrc.src[4]=Wv2;
  wsrc.src[5]=Wz; wsrc.src[6]=Wm;
  wtrans_all<<<dim3(2592), 256, 0, stream>>>(wsrc, ws);

  ConvPtrs ph;
  ph.W[0]=WtQ;  ph.W[1]=WtK;  ph.W[2]=WtV;
  ph.bias[0]=bq; ph.bias[1]=bk; ph.bias[2]=bv;
  ph.out[0]=slotA; ph.out[1]=slotB; ph.out[2]=slotC;
  ph.vt[0]=0; ph.vt[1]=0; ph.vt[2]=1;
  conv64_mfma<3><<<dim3(BB*HH), 256, 0, stream>>>(h, ph);

  ConvPtrs pm;
  pm.W[0]=WtK2; pm.W[1]=WtV2; pm.W[2]=WtV2;
  pm.bias[0]=bk2; pm.bias[1]=bv2; pm.bias[2]=bv2;
  pm.out[0]=slotD; pm.out[1]=slotE; pm.out[2]=slotE;
  pm.vt[0]=0; pm.vt[1]=1; pm.vt[2]=1;
  conv64_mfma<2><<<dim3(BB*HH), 256, 0, stream>>>(m, pm);

  // split-K fused dual attention -> partials in d_out + (m,l) in ws
  attn2_mfma<<<dim3(NSEQ/32, BB, 2), 256, 0, stream>>>(
      slotA, slotB, slotC, slotD, slotE, po, ml);

  // combine chunk pairs -> z_h, z_m (in-place in d_out)
  attn_combine<<<dim3(2048), 256, 0, stream>>>(po, ml);

  // Z = conv(concat(z_h, z_m)) -> bf16 into Zb (q, k_h slots dead)
  bigconv_mfma<128,128,64,false,false><<<dim3(BB*HH), 256, 0, stream>>>(
      zh, zm, (const float*)0, WtZ, bz, (void*)Zb, (void*)0, (const float*)0);

  // combined = conv(concat(Z, h)); fused gating -> f32 outputs
  bigconv_mfma<192,192,128,true,true><<<dim3(BB*HH), 256, 0, stream>>>(
      Zb, (const u16*)0, h, WtM, bm, (void*)outh, (void*)outm, m);
}

// Round 12
// 194.221 us; speedup vs baseline: 15.2380x; 1.1416x over previous
//
#include <hip/hip_runtime.h>

#define BB 8
#define HH 48
#define WW 48
#define DD 64
#define NSEQ (HH*WW)   // 2304

typedef unsigned short u16;
typedef unsigned long long u64;
typedef __attribute__((ext_vector_type(8))) short short8;
typedef __attribute__((ext_vector_type(4))) float f32x4;

__device__ __forceinline__ float bf2f(u16 u){ return __uint_as_float(((unsigned)u)<<16); }
__device__ __forceinline__ u16 f2bf(float f){
  unsigned u = __float_as_uint(f);
  return (u16)((u + 0x7fffu + ((u>>16)&1u)) >> 16);   // RNE
}
__device__ __forceinline__ f32x4 mfma16(short8 a, short8 b, f32x4 c){
  return __builtin_amdgcn_mfma_f32_16x16x32_bf16(a, b, c, 0, 0, 0);
}

// ------- fused weight transpose: all 7 tensors, [9][CI][CO] f32 -> [9][CO][CI] bf16 ----
struct WtSrcs { const float* src[7]; };
__global__ __launch_bounds__(256) void wtrans_all(WtSrcs s, u16* __restrict__ dst){
  int i = blockIdx.x*256 + threadIdx.x;       // total 663552
  if(i >= 663552) return;
  const float* sp; int local, CI;
  if(i < 184320){ int seg = i/36864; local = i - seg*36864; sp = s.src[seg]; CI = 64; }
  else if(i < 331776){ local = i - 184320; sp = s.src[5]; CI = 128; }
  else { local = i - 331776; sp = s.src[6]; CI = 192; }
  int per = CI*CI;
  int kk = local / per, rem = local % per;
  int co = rem / CI, ci = rem % CI;
  dst[i] = f2bf(sp[kk*per + ci*CI + co]);
}

// ---------------- multi-conv 64->64 (MFMA); optional transposed [b][co][seq] output ----
struct ConvPtrs {
  const u16*   W[3];     // bf16 [9][co][ci]
  const float* bias[3];  // f32
  u16*         out[3];   // bf16
  int          vt[3];    // 1 -> write transposed [b][co][seq]
};

template<int NC>
__global__ __launch_bounds__(256) void conv64_mfma(const float* __restrict__ in, ConvPtrs p){
  const int SP = 72;
  __shared__ u16 lds[3][WW+2][SP];
  const int b = blockIdx.x / HH, y = blockIdx.x % HH;
  const int tid  = threadIdx.x;
  const int wave = tid >> 6, lane = tid & 63, g = lane >> 4, col = lane & 15;
  const short8 Z8 = {0,0,0,0,0,0,0,0};

  for(int ky=0; ky<3; ky++){
    int ys = y + ky - 1;
    const int NCH = WW*64/8;
    if(ys < 0 || ys >= HH){
      for(int c8 = tid; c8 < NCH; c8 += 256){
        int px = c8 >> 3, cb = (c8 & 7)*8;
        *(short8*)&lds[ky][px+1][cb] = Z8;
      }
    } else {
      const float* rowp = in + (size_t)(b*HH + ys)*WW*64;
      for(int c8 = tid; c8 < NCH; c8 += 256){
        int px = c8 >> 3, cb = (c8 & 7)*8;
        short8 v;
        #pragma unroll
        for(int j=0;j<8;j++) v[j] = (short)f2bf(rowp[px*64 + cb + j]);
        *(short8*)&lds[ky][px+1][cb] = v;
      }
    }
    for(int c8 = tid; c8 < 16; c8 += 256){
      int which = c8 >> 3; int cb = (c8 & 7)*8;
      *(short8*)&lds[ky][which ? (WW+1) : 0][cb] = Z8;
    }
  }
  __syncthreads();

  const f32x4 zf = {0.f,0.f,0.f,0.f};
  f32x4 acc[3][NC];
  #pragma unroll
  for(int mt=0; mt<3; mt++)
    #pragma unroll
    for(int c=0; c<NC; c++) acc[mt][c] = zf;

  #pragma unroll
  for(int ky=0; ky<3; ky++)
  #pragma unroll
  for(int kx=0; kx<3; kx++)
  #pragma unroll
  for(int ks=0; ks<2; ks++){
    short8 a[3];
    #pragma unroll
    for(int mt=0; mt<3; mt++)
      a[mt] = *(const short8*)&lds[ky][mt*16 + col + kx][ks*32 + g*8];
    #pragma unroll
    for(int c=0; c<NC; c++){
      const u16* wp = p.W[c] + ((size_t)((ky*3+kx)*64) + (wave*16 + col))*64 + ks*32 + g*8;
      short8 bfr = *(const short8*)wp;
      #pragma unroll
      for(int mt=0; mt<3; mt++)
        acc[mt][c] = mfma16(a[mt], bfr, acc[mt][c]);
    }
  }

  #pragma unroll
  for(int c=0; c<NC; c++){
    int co = wave*16 + col;
    float bs = p.bias[c][co];
    if(p.vt[c]){
      u16* op = p.out[c] + ((size_t)(b*64 + co))*NSEQ + (size_t)y*WW;
      #pragma unroll
      for(int mt=0; mt<3; mt++){
        int px = mt*16 + g*4;
        u64 pk =  (u64)f2bf(acc[mt][c][0] + bs)
               | ((u64)f2bf(acc[mt][c][1] + bs) << 16)
               | ((u64)f2bf(acc[mt][c][2] + bs) << 32)
               | ((u64)f2bf(acc[mt][c][3] + bs) << 48);
        *(u64*)&op[px] = pk;
      }
    } else {
      u16* op = p.out[c] + ((size_t)(b*HH + y)*WW)*64 + co;
      #pragma unroll
      for(int mt=0; mt<3; mt++)
        #pragma unroll
        for(int r=0; r<4; r++){
          int px = mt*16 + g*4 + r;
          op[(size_t)px*64] = f2bf(acc[mt][c][r] + bs);
        }
    }
  }
}

// ------- split-K single-stream flash attention: QBLK=64, 4 strip-waves ---------------
// blockIdx.z = stream*2 + chunk. Emits UNNORMALIZED partial O (bf16) + per-row (m,l).
// po regions (u16): [h-c0][h-c1][m-c0][m-c1], each NPIX.
__global__ __launch_bounds__(256) void attn2_mfma(
    const u16* __restrict__ q,
    const u16* __restrict__ kh, const u16* __restrict__ vhT,
    const u16* __restrict__ km2, const u16* __restrict__ vmT,
    u16* __restrict__ po, float2* __restrict__ ml){
  __shared__ u16 Ks [64*64];    // [key][d] swizzled
  __shared__ u16 Vts[64*64];    // [d][key] swizzled
  __shared__ u16 Ps [64*64];    // [qrow][key] swizzled (wave-private strips)
  const int qt = blockIdx.x, b = blockIdx.y;
  const int s = blockIdx.z >> 1, ch = blockIdx.z & 1;
  const int tid = threadIdx.x, wave = tid>>6, lane = tid&63;
  const int g = lane>>4, col = lane&15;
  const int strip = wave;
  const size_t NP = (size_t)BB*NSEQ*DD;

  const u16* kk = s ? km2 : kh;
  const u16* vT = s ? vmT : vhT;

  const u16* qp = q + ((size_t)(b*NSEQ + qt*64 + strip*16 + col))*DD;
  short8 aq0 = *(const short8*)&qp[g*8];
  short8 aq1 = *(const short8*)&qp[32 + g*8];

  const int r0a = tid>>3, gr = tid&7, cb0 = gr*8;
  const int r0b = r0a + 32;
  const int stA = r0a*64 + ((gr ^ (r0a&7))<<3);
  const int stB = stA + 32*64;
  const size_t tb  = (size_t)(b*NSEQ)*DD;
  const size_t tbT = (size_t)(b*64)*NSEQ;

  const int cg0 = ((g     ^ (col&7))<<3);
  const int cg1 = (((4+g) ^ (col&7))<<3);

  short8 paK0,paK1,paV0,paV1;
  short8 pbK0,pbK1,pbV0,pbV1;

  const f32x4 zf = {0.f,0.f,0.f,0.f};
  f32x4 o[4];
  #pragma unroll
  for(int nt=0; nt<4; nt++) o[nt] = zf;
  float mst[4], lst[4];
  #pragma unroll
  for(int r=0; r<4; r++){ mst[r] = -1e30f; lst[r] = 0.f; }

#define BAR() { __builtin_amdgcn_s_barrier(); __builtin_amdgcn_sched_barrier(0); }
#define LWAIT() { asm volatile("s_waitcnt lgkmcnt(0)" ::: "memory"); __builtin_amdgcn_sched_barrier(0); }

#define LOADSET(K0,K1,V0,V1, kt_) {                                        \
    size_t offK0 = tb + (size_t)(kt_)*64*DD + (size_t)r0a*DD + cb0;        \
    size_t offK1 = tb + (size_t)(kt_)*64*DD + (size_t)r0b*DD + cb0;        \
    size_t offV0 = tbT + (size_t)r0a*NSEQ + (size_t)(kt_)*64 + cb0;        \
    size_t offV1 = tbT + (size_t)r0b*NSEQ + (size_t)(kt_)*64 + cb0;        \
    K0 = *(const short8*)&kk[offK0];  K1 = *(const short8*)&kk[offK1];     \
    V0 = *(const short8*)&vT[offV0];  V1 = *(const short8*)&vT[offV1];     \
  }
#define STORESET(K0,K1,V0,V1) {                                            \
    *(short8*)&Ks [stA] = K0;   *(short8*)&Ks [stB] = K1;                  \
    *(short8*)&Vts[stA] = V0;   *(short8*)&Vts[stB] = V1;                  \
  }
#define COMPUTE() {                                                 \
    __builtin_amdgcn_s_setprio(1);                                  \
    f32x4 sv[4];                                                    \
    _Pragma("unroll")                                               \
    for(int nt=0; nt<4; nt++){                                      \
      sv[nt] = zf;                                                  \
      int rowb = (nt*16 + col)*64;                                  \
      short8 bk0 = *(const short8*)&Ks[rowb + cg0];                 \
      sv[nt] = mfma16(aq0, bk0, sv[nt]);                            \
      short8 bk1 = *(const short8*)&Ks[rowb + cg1];                 \
      sv[nt] = mfma16(aq1, bk1, sv[nt]);                            \
    }                                                               \
    _Pragma("unroll")                                               \
    for(int r=0; r<4; r++){                                         \
      float mx = fmaxf(fmaxf(sv[0][r], sv[1][r]), fmaxf(sv[2][r], sv[3][r])); \
      mx = fmaxf(mx, __shfl_xor(mx, 8));                            \
      mx = fmaxf(mx, __shfl_xor(mx, 4));                            \
      mx = fmaxf(mx, __shfl_xor(mx, 2));                            \
      mx = fmaxf(mx, __shfl_xor(mx, 1));                            \
      float mnew = fmaxf(mst[r], mx);                               \
      float scale = __expf(mst[r] - mnew);                          \
      mst[r] = mnew;                                                \
      lst[r] *= scale;                                              \
      _Pragma("unroll")                                             \
      for(int nt=0; nt<4; nt++) o[nt][r] *= scale;                  \
      float rs = 0.f;                                               \
      _Pragma("unroll")                                             \
      for(int nt=0; nt<4; nt++){                                    \
        float pv = __expf(sv[nt][r] - mnew);                        \
        sv[nt][r] = pv;                                             \
        rs += pv;                                                   \
      }                                                             \
      rs += __shfl_xor(rs, 8);                                      \
      rs += __shfl_xor(rs, 4);                                      \
      rs += __shfl_xor(rs, 2);                                      \
      rs += __shfl_xor(rs, 1);                                      \
      lst[r] += rs;                                                 \
      int prow = strip*16 + g*4 + r;                                \
      int pbase = prow*64;                                          \
      _Pragma("unroll")                                             \
      for(int nt=0; nt<4; nt++)                                     \
        Ps[pbase + (((nt*2 + (col>>3)) ^ (prow&7))<<3) + (col&7)] = f2bf(sv[nt][r]); \
    }                                                               \
    int prowr = strip*16 + col;                                     \
    _Pragma("unroll")                                               \
    for(int ks=0; ks<2; ks++){                                      \
      short8 ap = *(const short8*)&Ps[prowr*64 + (ks ? cg1 : cg0)]; \
      _Pragma("unroll")                                             \
      for(int nt=0; nt<4; nt++){                                    \
        short8 bv = *(const short8*)&Vts[(nt*16 + col)*64 + (ks ? cg1 : cg0)]; \
        o[nt] = mfma16(ap, bv, o[nt]);                              \
      }                                                             \
    }                                                               \
    __builtin_amdgcn_s_setprio(0);                                  \
  }

  const int kt0 = ch*18;                     // 18 tiles of 64 keys per chunk
  LOADSET(paK0,paK1,paV0,paV1, kt0);
  for(int kt = kt0; kt < kt0+18; kt += 2){
    LOADSET(pbK0,pbK1,pbV0,pbV1, kt+1);
    BAR();
    STORESET(paK0,paK1,paV0,paV1);
    LWAIT();
    BAR();
    COMPUTE();
    if(kt+2 < kt0+18) LOADSET(paK0,paK1,paV0,paV1, kt+2);
    BAR();
    STORESET(pbK0,pbK1,pbV0,pbV1);
    LWAIT();
    BAR();
    COMPUTE();
  }

  // unnormalized partial O + (m,l)
  u16* pb = po + (size_t)(s*2 + ch)*NP + ((size_t)(b*NSEQ + qt*64 + strip*16))*DD;
  #pragma unroll
  for(int nt=0; nt<4; nt++)
    #pragma unroll
    for(int r=0; r<4; r++)
      pb[(g*4 + r)*DD + nt*16 + col] = f2bf(o[nt][r]);
  if(col == 0){
    #pragma unroll
    for(int r=0; r<4; r++){
      int qrow = qt*64 + strip*16 + g*4 + r;
      float2 v; v.x = mst[r]; v.y = lst[r];
      ml[(size_t)(s*2 + ch)*BB*NSEQ + (size_t)b*NSEQ + qrow] = v;
    }
  }
#undef LOADSET
#undef STORESET
#undef COMPUTE
#undef BAR
#undef LWAIT
}

// ------- combine 2 KV-chunks: in-place into po regions 0 (z_h) and 1 (z_m) -----------
__global__ __launch_bounds__(256) void attn_combine(u16* po, const float2* ml){
  const size_t NP = (size_t)BB*NSEQ*DD;
  const size_t RORD = (size_t)BB*NSEQ;
  for(size_t e = (size_t)blockIdx.x*256 + threadIdx.x; e < NP; e += (size_t)gridDim.x*256){
    size_t row = e / DD;
    float2 h0 = ml[row],         h1 = ml[RORD + row];
    float2 m0 = ml[2*RORD + row], m1 = ml[3*RORD + row];
    float oh0 = bf2f(po[e]),      oh1 = bf2f(po[NP + e]);
    float om0 = bf2f(po[2*NP + e]), om1 = bf2f(po[3*NP + e]);
    float M  = fmaxf(h0.x, h1.x);
    float a0 = __expf(h0.x - M), a1 = __expf(h1.x - M);
    float vh = (a0*oh0 + a1*oh1) / (a0*h0.y + a1*h1.y);
    M  = fmaxf(m0.x, m1.x);
    a0 = __expf(m0.x - M); a1 = __expf(m1.x - M);
    float vm = (a0*om0 + a1*om1) / (a0*m0.y + a1*m1.y);
    po[e]      = f2bf(vh);     // z_h
    po[NP + e] = f2bf(vm);     // z_m (overwrites h-c1, read by this thread only)
  }
}

// -------- big conv (MFMA, concat input): in0 bf16; in1 bf16 or f32; GATE -> f32 out ----
template<int CIN, int COUT, int SPLIT, bool GATE, bool IN1F>
__global__ __launch_bounds__(256) void bigconv_mfma(
    const u16* __restrict__ in0, const u16* __restrict__ in1b, const float* __restrict__ in1f,
    const u16* __restrict__ Wt, const float* __restrict__ bias,
    void* __restrict__ out0v, void* __restrict__ out1v, const float* __restrict__ mem){
  constexpr int SP  = CIN + 8;
  constexpr int NTW = COUT/64;
  __shared__ u16 lds[3][WW+2][SP];
  const int b = blockIdx.x / HH, y = blockIdx.x % HH;
  const int tid  = threadIdx.x;
  const int wave = tid >> 6, lane = tid & 63, g = lane >> 4, col = lane & 15;
  const short8 Z8 = {0,0,0,0,0,0,0,0};

  for(int ky=0; ky<3; ky++){
    int ys = y + ky - 1;
    const int NCH = WW*CIN/8;
    if(ys < 0 || ys >= HH){
      for(int c8 = tid; c8 < NCH; c8 += 256){
        int px = c8 / (CIN/8), cb = (c8 % (CIN/8))*8;
        *(short8*)&lds[ky][px+1][cb] = Z8;
      }
    } else {
      size_t base0 = (size_t)(b*HH + ys)*WW*SPLIT;
      size_t base1 = (size_t)(b*HH + ys)*WW*(CIN-SPLIT);
      for(int c8 = tid; c8 < NCH; c8 += 256){
        int px = c8 / (CIN/8), cb = (c8 % (CIN/8))*8;
        short8 val;
        if(cb < SPLIT){
          val = *(const short8*)&in0[base0 + (size_t)px*SPLIT + cb];
        } else if constexpr (IN1F){
          const float* sp = &in1f[base1 + (size_t)px*(CIN-SPLIT) + cb - SPLIT];
          #pragma unroll
          for(int j=0;j<8;j++) val[j] = (short)f2bf(sp[j]);
        } else {
          val = *(const short8*)&in1b[base1 + (size_t)px*(CIN-SPLIT) + cb - SPLIT];
        }
        *(short8*)&lds[ky][px+1][cb] = val;
      }
    }
    for(int c8 = tid; c8 < 2*(CIN/8); c8 += 256){
      int which = c8 / (CIN/8); int cb = (c8 % (CIN/8))*8;
      *(short8*)&lds[ky][which ? (WW+1) : 0][cb] = Z8;
    }
  }
  __syncthreads();

  const f32x4 zf = {0.f,0.f,0.f,0.f};
  f32x4 acc[3][NTW];
  #pragma unroll
  for(int mt=0; mt<3; mt++)
    #pragma unroll
    for(int i=0; i<NTW; i++) acc[mt][i] = zf;

  #pragma unroll
  for(int ky=0; ky<3; ky++)
  #pragma unroll
  for(int kx=0; kx<3; kx++)
  #pragma unroll
  for(int ks=0; ks<CIN/32; ks++){
    short8 a[3];
    #pragma unroll
    for(int mt=0; mt<3; mt++)
      a[mt] = *(const short8*)&lds[ky][mt*16 + col + kx][ks*32 + g*8];
    #pragma unroll
    for(int i=0; i<NTW; i++){
      int co0 = (wave + 4*i)*16;
      const u16* wp = Wt + ((size_t)((ky*3+kx)*COUT) + co0 + col)*CIN + ks*32 + g*8;
      short8 bfr = *(const short8*)wp;
      #pragma unroll
      for(int mt=0; mt<3; mt++)
        acc[mt][i] = mfma16(a[mt], bfr, acc[mt][i]);
    }
  }

  if constexpr (!GATE){
    u16* out0 = (u16*)out0v;
    #pragma unroll
    for(int i=0; i<NTW; i++){
      int co = (wave + 4*i)*16 + col;
      float bs = bias[co];
      u16* op = out0 + (size_t)(b*HH + y)*WW*COUT + co;
      #pragma unroll
      for(int mt=0; mt<3; mt++)
        #pragma unroll
        for(int r=0; r<4; r++){
          int px = mt*16 + g*4 + r;
          op[(size_t)px*COUT] = f2bf(acc[mt][i][r] + bs);
        }
    }
  } else {
    float* oh = (float*)out0v;
    float* om = (float*)out1v;
    int c = wave*16 + col;
    float bo = bias[c], bg = bias[64+c], bgi = bias[128+c];
    #pragma unroll
    for(int mt=0; mt<3; mt++)
      #pragma unroll
      for(int r=0; r<4; r++){
        int px = mt*16 + g*4 + r;
        size_t idx = ((size_t)(b*HH + y)*WW + px)*64 + c;
        float mo = acc[mt][0][r] + bo;
        float mg = acc[mt][1][r] + bg;
        float gi = acc[mt][2][r] + bgi;
        float mval = mem[idx];
        float si = 1.f/(1.f + __expf(-gi));
        float nm = (1.f - si)*mval + si*tanhf(mg);
        float nh = (1.f/(1.f + __expf(-mo)))*nm;
        oh[idx] = nh;
        om[idx] = nm;
      }
  }
}

// ---------------- launcher ----------------
extern "C" void kernel_launch(void* const* d_in, const int* in_sizes, int n_in,
                              void* d_out, int out_size, void* d_ws, size_t ws_size,
                              hipStream_t stream){
  (void)in_sizes; (void)n_in; (void)out_size; (void)ws_size;
  const float* h   = (const float*)d_in[0];
  const float* m   = (const float*)d_in[1];
  const float* Wq  = (const float*)d_in[2];  const float* bq  = (const float*)d_in[3];
  const float* Wk  = (const float*)d_in[4];  const float* bk  = (const float*)d_in[5];
  const float* Wk2 = (const float*)d_in[6];  const float* bk2 = (const float*)d_in[7];
  const float* Wv  = (const float*)d_in[8];  const float* bv  = (const float*)d_in[9];
  const float* Wv2 = (const float*)d_in[10]; const float* bv2 = (const float*)d_in[11];
  const float* Wz  = (const float*)d_in[12]; const float* bz  = (const float*)d_in[13];
  const float* Wm  = (const float*)d_in[14]; const float* bm  = (const float*)d_in[15];

  const size_t NPIX = (size_t)BB*NSEQ*DD;  // 1,179,648

  u16* ws = (u16*)d_ws;
  u16* WtQ  = ws + 0;            // all 7 transposed weights contiguous: 663552 u16
  u16* WtK  = ws + 36864;
  u16* WtK2 = ws + 73728;
  u16* WtV  = ws + 110592;
  u16* WtV2 = ws + 147456;
  u16* WtZ  = ws + 184320;
  u16* WtM  = ws + 331776;
  u16* slotA = ws + 663552;      // q;   later Z low half
  u16* slotB = slotA + NPIX;     // k_h; later Z high half
  u16* slotC = slotB + NPIX;     // v_h^T [b][d][seq]
  u16* slotD = slotC + NPIX;     // k_m
  u16* slotE = slotD + NPIX;     // v_m^T [b][d][seq]
  float2* ml = (float2*)(ws + 663552 + 5*NPIX);   // 4*BB*NSEQ float2 = 590 KB
  u16* Zb    = slotA;            // 2*NPIX spanning A+B

  float* outh = (float*)d_out;   // final new_h (f32)
  float* outm = outh + NPIX;     // final new_m (f32)
  u16* po = (u16*)d_out;         // partial-O regions [h-c0][h-c1][m-c0][m-c1], 4*NPIX u16
  u16* zh = po;                  // after combine: z_h
  u16* zm = po + NPIX;           // after combine: z_m

  WtSrcs wsrc;
  wsrc.src[0]=Wq; wsrc.src[1]=Wk; wsrc.src[2]=Wk2; wsrc.src[3]=Wv; wsrc.src[4]=Wv2;
  wsrc.src[5]=Wz; wsrc.src[6]=Wm;
  wtrans_all<<<dim3(2592), 256, 0, stream>>>(wsrc, ws);

  ConvPtrs ph;
  ph.W[0]=WtQ;  ph.W[1]=WtK;  ph.W[2]=WtV;
  ph.bias[0]=bq; ph.bias[1]=bk; ph.bias[2]=bv;
  ph.out[0]=slotA; ph.out[1]=slotB; ph.out[2]=slotC;
  ph.vt[0]=0; ph.vt[1]=0; ph.vt[2]=1;
  conv64_mfma<3><<<dim3(BB*HH), 256, 0, stream>>>(h, ph);

  ConvPtrs pm;
  pm.W[0]=WtK2; pm.W[1]=WtV2; pm.W[2]=WtV2;
  pm.bias[0]=bk2; pm.bias[1]=bv2; pm.bias[2]=bv2;
  pm.out[0]=slotD; pm.out[1]=slotE; pm.out[2]=slotE;
  pm.vt[0]=0; pm.vt[1]=1; pm.vt[2]=1;
  conv64_mfma<2><<<dim3(BB*HH), 256, 0, stream>>>(m, pm);

  // stream-split + split-K attention -> partials in d_out + (m,l) in ws
  attn2_mfma<<<dim3(NSEQ/64, BB, 4), 256, 0, stream>>>(
      slotA, slotB, slotC, slotD, slotE, po, ml);

  // combine chunk pairs -> z_h, z_m (in-place in d_out)
  attn_combine<<<dim3(2048), 256, 0, stream>>>(po, ml);

  // Z = conv(concat(z_h, z_m)) -> bf16 into Zb (q, k_h slots dead)
  bigconv_mfma<128,128,64,false,false><<<dim3(BB*HH), 256, 0, stream>>>(
      zh, zm, (const float*)0, WtZ, bz, (void*)Zb, (void*)0, (const float*)0);

  // combined = conv(concat(Z, h)); fused gating -> f32 outputs
  bigconv_mfma<192,192,128,true,true><<<dim3(BB*HH), 256, 0, stream>>>(
      Zb, (const u16*)0, h, WtM, bm, (void*)outh, (void*)outm, m);
}

// Round 13
// 185.059 us; speedup vs baseline: 15.9923x; 1.0495x over previous
//
#include <hip/hip_runtime.h>

#define BB 8
#define HH 48
#define WW 48
#define DD 64
#define NSEQ (HH*WW)   // 2304

typedef unsigned short u16;
typedef unsigned long long u64;
typedef __attribute__((ext_vector_type(8))) short short8;
typedef __attribute__((ext_vector_type(4))) float f32x4;

__device__ __forceinline__ float bf2f(u16 u){ return __uint_as_float(((unsigned)u)<<16); }
__device__ __forceinline__ u16 f2bf(float f){
  unsigned u = __float_as_uint(f);
  return (u16)((u + 0x7fffu + ((u>>16)&1u)) >> 16);   // RNE
}
__device__ __forceinline__ f32x4 mfma16(short8 a, short8 b, f32x4 c){
  return __builtin_amdgcn_mfma_f32_16x16x32_bf16(a, b, c, 0, 0, 0);
}

// ------- fused weight transpose: all 7 tensors, [9][CI][CO] f32 -> [9][CO][CI] bf16 ----
struct WtSrcs { const float* src[7]; };
__global__ __launch_bounds__(256) void wtrans_all(WtSrcs s, u16* __restrict__ dst){
  int i = blockIdx.x*256 + threadIdx.x;       // total 663552
  if(i >= 663552) return;
  const float* sp; int local, CI;
  if(i < 184320){ int seg = i/36864; local = i - seg*36864; sp = s.src[seg]; CI = 64; }
  else if(i < 331776){ local = i - 184320; sp = s.src[5]; CI = 128; }
  else { local = i - 331776; sp = s.src[6]; CI = 192; }
  int per = CI*CI;
  int kk = local / per, rem = local % per;
  int co = rem / CI, ci = rem % CI;
  dst[i] = f2bf(sp[kk*per + ci*CI + co]);
}

// ----- merged multi-conv 64->64 (MFMA): blockIdx.z=0 -> h stream, =1 -> m stream ------
struct ConvPtrs {
  const u16*   W[3];     // bf16 [9][co][ci]
  const float* bias[3];  // f32
  u16*         out[3];   // bf16
  int          vt[3];    // 1 -> write transposed [b][co][seq]
  int          nc;       // active weight sets
};

__global__ __launch_bounds__(256) void conv64_mfma(
    const float* __restrict__ in0, const float* __restrict__ in1,
    ConvPtrs p0, ConvPtrs p1){
  const int SP = 72;
  __shared__ u16 lds[3][WW+2][SP];
  const float* in = blockIdx.z ? in1 : in0;
  ConvPtrs p = blockIdx.z ? p1 : p0;
  const int b = blockIdx.x / HH, y = blockIdx.x % HH;
  const int tid  = threadIdx.x;
  const int wave = tid >> 6, lane = tid & 63, g = lane >> 4, col = lane & 15;
  const short8 Z8 = {0,0,0,0,0,0,0,0};

  for(int ky=0; ky<3; ky++){
    int ys = y + ky - 1;
    const int NCH = WW*64/8;
    if(ys < 0 || ys >= HH){
      for(int c8 = tid; c8 < NCH; c8 += 256){
        int px = c8 >> 3, cb = (c8 & 7)*8;
        *(short8*)&lds[ky][px+1][cb] = Z8;
      }
    } else {
      const float* rowp = in + (size_t)(b*HH + ys)*WW*64;
      for(int c8 = tid; c8 < NCH; c8 += 256){
        int px = c8 >> 3, cb = (c8 & 7)*8;
        short8 v;
        #pragma unroll
        for(int j=0;j<8;j++) v[j] = (short)f2bf(rowp[px*64 + cb + j]);
        *(short8*)&lds[ky][px+1][cb] = v;
      }
    }
    for(int c8 = tid; c8 < 16; c8 += 256){
      int which = c8 >> 3; int cb = (c8 & 7)*8;
      *(short8*)&lds[ky][which ? (WW+1) : 0][cb] = Z8;
    }
  }
  __syncthreads();

  const f32x4 zf = {0.f,0.f,0.f,0.f};
  f32x4 acc[3][3];
  #pragma unroll
  for(int mt=0; mt<3; mt++)
    #pragma unroll
    for(int c=0; c<3; c++) acc[mt][c] = zf;

  const int nc = p.nc;
  #pragma unroll
  for(int ky=0; ky<3; ky++)
  #pragma unroll
  for(int kx=0; kx<3; kx++)
  #pragma unroll
  for(int ks=0; ks<2; ks++){
    short8 a[3];
    #pragma unroll
    for(int mt=0; mt<3; mt++)
      a[mt] = *(const short8*)&lds[ky][mt*16 + col + kx][ks*32 + g*8];
    #pragma unroll
    for(int c=0; c<3; c++){
      if(c < nc){
        const u16* wp = p.W[c] + ((size_t)((ky*3+kx)*64) + (wave*16 + col))*64 + ks*32 + g*8;
        short8 bfr = *(const short8*)wp;
        #pragma unroll
        for(int mt=0; mt<3; mt++)
          acc[mt][c] = mfma16(a[mt], bfr, acc[mt][c]);
      }
    }
  }

  #pragma unroll
  for(int c=0; c<3; c++){
    if(c >= nc) continue;
    int co = wave*16 + col;
    float bs = p.bias[c][co];
    if(p.vt[c]){
      u16* op = p.out[c] + ((size_t)(b*64 + co))*NSEQ + (size_t)y*WW;
      #pragma unroll
      for(int mt=0; mt<3; mt++){
        int px = mt*16 + g*4;
        u64 pk =  (u64)f2bf(acc[mt][c][0] + bs)
               | ((u64)f2bf(acc[mt][c][1] + bs) << 16)
               | ((u64)f2bf(acc[mt][c][2] + bs) << 32)
               | ((u64)f2bf(acc[mt][c][3] + bs) << 48);
        *(u64*)&op[px] = pk;
      }
    } else {
      u16* op = p.out[c] + ((size_t)(b*HH + y)*WW)*64 + co;
      #pragma unroll
      for(int mt=0; mt<3; mt++)
        #pragma unroll
        for(int r=0; r<4; r++){
          int px = mt*16 + g*4 + r;
          op[(size_t)px*64] = f2bf(acc[mt][c][r] + bs);
        }
    }
  }
}

// ------- split-K single-stream flash attention: QBLK=64, 4 strip-waves ---------------
// blockIdx.z = stream*3 + chunk (3 chunks of 12 tiles). Emits UNNORMALIZED partial O
// (bf16) + per-row (m,l). Regions 0..3 live in po (d_out), 4..5 in pox (ws).
__global__ __launch_bounds__(256) void attn2_mfma(
    const u16* __restrict__ q,
    const u16* __restrict__ kh, const u16* __restrict__ vhT,
    const u16* __restrict__ km2, const u16* __restrict__ vmT,
    u16* __restrict__ po, u16* __restrict__ pox, float2* __restrict__ ml){
  __shared__ u16 Ks [64*64];    // [key][d] swizzled
  __shared__ u16 Vts[64*64];    // [d][key] swizzled
  __shared__ u16 Ps [64*64];    // [qrow][key] swizzled (wave-private strips)
  const int qt = blockIdx.x, b = blockIdx.y;
  const int s = blockIdx.z / 3, ch = blockIdx.z % 3;
  const int tid = threadIdx.x, wave = tid>>6, lane = tid&63;
  const int g = lane>>4, col = lane&15;
  const int strip = wave;
  const size_t NP = (size_t)BB*NSEQ*DD;

  const u16* kk = s ? km2 : kh;
  const u16* vT = s ? vmT : vhT;

  const u16* qp = q + ((size_t)(b*NSEQ + qt*64 + strip*16 + col))*DD;
  short8 aq0 = *(const short8*)&qp[g*8];
  short8 aq1 = *(const short8*)&qp[32 + g*8];

  const int r0a = tid>>3, gr = tid&7, cb0 = gr*8;
  const int r0b = r0a + 32;
  const int stA = r0a*64 + ((gr ^ (r0a&7))<<3);
  const int stB = stA + 32*64;
  const size_t tb  = (size_t)(b*NSEQ)*DD;
  const size_t tbT = (size_t)(b*64)*NSEQ;

  const int cg0 = ((g     ^ (col&7))<<3);
  const int cg1 = (((4+g) ^ (col&7))<<3);

  short8 paK0,paK1,paV0,paV1;
  short8 pbK0,pbK1,pbV0,pbV1;

  const f32x4 zf = {0.f,0.f,0.f,0.f};
  f32x4 o[4];
  #pragma unroll
  for(int nt=0; nt<4; nt++) o[nt] = zf;
  float mst[4], lst[4];
  #pragma unroll
  for(int r=0; r<4; r++){ mst[r] = -1e30f; lst[r] = 0.f; }

#define BAR() { __builtin_amdgcn_s_barrier(); __builtin_amdgcn_sched_barrier(0); }
#define LWAIT() { asm volatile("s_waitcnt lgkmcnt(0)" ::: "memory"); __builtin_amdgcn_sched_barrier(0); }

#define LOADSET(K0,K1,V0,V1, kt_) {                                        \
    size_t offK0 = tb + (size_t)(kt_)*64*DD + (size_t)r0a*DD + cb0;        \
    size_t offK1 = tb + (size_t)(kt_)*64*DD + (size_t)r0b*DD + cb0;        \
    size_t offV0 = tbT + (size_t)r0a*NSEQ + (size_t)(kt_)*64 + cb0;        \
    size_t offV1 = tbT + (size_t)r0b*NSEQ + (size_t)(kt_)*64 + cb0;        \
    K0 = *(const short8*)&kk[offK0];  K1 = *(const short8*)&kk[offK1];     \
    V0 = *(const short8*)&vT[offV0];  V1 = *(const short8*)&vT[offV1];     \
  }
#define STORESET(K0,K1,V0,V1) {                                            \
    *(short8*)&Ks [stA] = K0;   *(short8*)&Ks [stB] = K1;                  \
    *(short8*)&Vts[stA] = V0;   *(short8*)&Vts[stB] = V1;                  \
  }
#define COMPUTE() {                                                 \
    __builtin_amdgcn_s_setprio(1);                                  \
    f32x4 sv[4];                                                    \
    _Pragma("unroll")                                               \
    for(int nt=0; nt<4; nt++){                                      \
      sv[nt] = zf;                                                  \
      int rowb = (nt*16 + col)*64;                                  \
      short8 bk0 = *(const short8*)&Ks[rowb + cg0];                 \
      sv[nt] = mfma16(aq0, bk0, sv[nt]);                            \
      short8 bk1 = *(const short8*)&Ks[rowb + cg1];                 \
      sv[nt] = mfma16(aq1, bk1, sv[nt]);                            \
    }                                                               \
    _Pragma("unroll")                                               \
    for(int r=0; r<4; r++){                                         \
      float mx = fmaxf(fmaxf(sv[0][r], sv[1][r]), fmaxf(sv[2][r], sv[3][r])); \
      mx = fmaxf(mx, __shfl_xor(mx, 8));                            \
      mx = fmaxf(mx, __shfl_xor(mx, 4));                            \
      mx = fmaxf(mx, __shfl_xor(mx, 2));                            \
      mx = fmaxf(mx, __shfl_xor(mx, 1));                            \
      float mnew = fmaxf(mst[r], mx);                               \
      float scale = __expf(mst[r] - mnew);                          \
      mst[r] = mnew;                                                \
      lst[r] *= scale;                                              \
      _Pragma("unroll")                                             \
      for(int nt=0; nt<4; nt++) o[nt][r] *= scale;                  \
      float rs = 0.f;                                               \
      _Pragma("unroll")                                             \
      for(int nt=0; nt<4; nt++){                                    \
        float pv = __expf(sv[nt][r] - mnew);                        \
        sv[nt][r] = pv;                                             \
        rs += pv;                                                   \
      }                                                             \
      rs += __shfl_xor(rs, 8);                                      \
      rs += __shfl_xor(rs, 4);                                      \
      rs += __shfl_xor(rs, 2);                                      \
      rs += __shfl_xor(rs, 1);                                      \
      lst[r] += rs;                                                 \
      int prow = strip*16 + g*4 + r;                                \
      int pbase = prow*64;                                          \
      _Pragma("unroll")                                             \
      for(int nt=0; nt<4; nt++)                                     \
        Ps[pbase + (((nt*2 + (col>>3)) ^ (prow&7))<<3) + (col&7)] = f2bf(sv[nt][r]); \
    }                                                               \
    int prowr = strip*16 + col;                                     \
    _Pragma("unroll")                                               \
    for(int ks=0; ks<2; ks++){                                      \
      short8 ap = *(const short8*)&Ps[prowr*64 + (ks ? cg1 : cg0)]; \
      _Pragma("unroll")                                             \
      for(int nt=0; nt<4; nt++){                                    \
        short8 bv = *(const short8*)&Vts[(nt*16 + col)*64 + (ks ? cg1 : cg0)]; \
        o[nt] = mfma16(ap, bv, o[nt]);                              \
      }                                                             \
    }                                                               \
    __builtin_amdgcn_s_setprio(0);                                  \
  }

  const int kt0 = ch*12;                     // 12 tiles of 64 keys per chunk
  LOADSET(paK0,paK1,paV0,paV1, kt0);
  for(int kt = kt0; kt < kt0+12; kt += 2){
    LOADSET(pbK0,pbK1,pbV0,pbV1, kt+1);
    BAR();
    STORESET(paK0,paK1,paV0,paV1);
    LWAIT();
    BAR();
    COMPUTE();
    if(kt+2 < kt0+12) LOADSET(paK0,paK1,paV0,paV1, kt+2);
    BAR();
    STORESET(pbK0,pbK1,pbV0,pbV1);
    LWAIT();
    BAR();
    COMPUTE();
  }

  // unnormalized partial O + (m,l)
  const int ridx = s*3 + ch;
  u16* rbase = (ridx < 4) ? (po + (size_t)ridx*NP) : (pox + (size_t)(ridx-4)*NP);
  u16* pb = rbase + ((size_t)(b*NSEQ + qt*64 + strip*16))*DD;
  #pragma unroll
  for(int nt=0; nt<4; nt++)
    #pragma unroll
    for(int r=0; r<4; r++)
      pb[(g*4 + r)*DD + nt*16 + col] = f2bf(o[nt][r]);
  if(col == 0){
    #pragma unroll
    for(int r=0; r<4; r++){
      int qrow = qt*64 + strip*16 + g*4 + r;
      float2 v; v.x = mst[r]; v.y = lst[r];
      ml[(size_t)ridx*BB*NSEQ + (size_t)b*NSEQ + qrow] = v;
    }
  }
#undef LOADSET
#undef STORESET
#undef COMPUTE
#undef BAR
#undef LWAIT
}

// ------- combine 3 KV-chunks per stream: z_h -> po region 0, z_m -> po region 1 -------
__global__ __launch_bounds__(256) void attn_combine(u16* po, const u16* __restrict__ pox,
                                                    const float2* __restrict__ ml){
  const size_t NP = (size_t)BB*NSEQ*DD;
  const size_t RORD = (size_t)BB*NSEQ;
  for(size_t e = (size_t)blockIdx.x*256 + threadIdx.x; e < NP; e += (size_t)gridDim.x*256){
    size_t row = e / DD;
    float2 sh[3], sm[3];
    float oh[3], om[3];
    #pragma unroll
    for(int c=0;c<3;c++){
      sh[c] = ml[(size_t)c*RORD + row];
      sm[c] = ml[(size_t)(3+c)*RORD + row];
      oh[c] = bf2f(po[(size_t)c*NP + e]);
      om[c] = (3+c < 4) ? bf2f(po[(size_t)(3+c)*NP + e]) : bf2f(pox[(size_t)(c-1)*NP + e]);
    }
    float M = fmaxf(fmaxf(sh[0].x, sh[1].x), sh[2].x);
    float num = 0.f, den = 0.f;
    #pragma unroll
    for(int c=0;c<3;c++){
      float a = __expf(sh[c].x - M);
      num += a*oh[c]; den += a*sh[c].y;
    }
    float vh = num/den;
    M = fmaxf(fmaxf(sm[0].x, sm[1].x), sm[2].x);
    num = 0.f; den = 0.f;
    #pragma unroll
    for(int c=0;c<3;c++){
      float a = __expf(sm[c].x - M);
      num += a*om[c]; den += a*sm[c].y;
    }
    float vm = num/den;
    po[e]      = f2bf(vh);     // z_h
    po[NP + e] = f2bf(vm);     // z_m (overwrites h-c1; this thread read it already)
  }
}

// -------- big conv (MFMA, concat input): in0 bf16; in1 bf16 or f32; GATE -> f32 out ----
template<int CIN, int COUT, int SPLIT, bool GATE, bool IN1F>
__global__ __launch_bounds__(256) void bigconv_mfma(
    const u16* __restrict__ in0, const u16* __restrict__ in1b, const float* __restrict__ in1f,
    const u16* __restrict__ Wt, const float* __restrict__ bias,
    void* __restrict__ out0v, void* __restrict__ out1v, const float* __restrict__ mem){
  constexpr int SP  = CIN + 8;
  constexpr int NTW = COUT/64;
  __shared__ u16 lds[3][WW+2][SP];
  const int b = blockIdx.x / HH, y = blockIdx.x % HH;
  const int tid  = threadIdx.x;
  const int wave = tid >> 6, lane = tid & 63, g = lane >> 4, col = lane & 15;
  const short8 Z8 = {0,0,0,0,0,0,0,0};

  for(int ky=0; ky<3; ky++){
    int ys = y + ky - 1;
    const int NCH = WW*CIN/8;
    if(ys < 0 || ys >= HH){
      for(int c8 = tid; c8 < NCH; c8 += 256){
        int px = c8 / (CIN/8), cb = (c8 % (CIN/8))*8;
        *(short8*)&lds[ky][px+1][cb] = Z8;
      }
    } else {
      size_t base0 = (size_t)(b*HH + ys)*WW*SPLIT;
      size_t base1 = (size_t)(b*HH + ys)*WW*(CIN-SPLIT);
      for(int c8 = tid; c8 < NCH; c8 += 256){
        int px = c8 / (CIN/8), cb = (c8 % (CIN/8))*8;
        short8 val;
        if(cb < SPLIT){
          val = *(const short8*)&in0[base0 + (size_t)px*SPLIT + cb];
        } else if constexpr (IN1F){
          const float* sp = &in1f[base1 + (size_t)px*(CIN-SPLIT) + cb - SPLIT];
          #pragma unroll
          for(int j=0;j<8;j++) val[j] = (short)f2bf(sp[j]);
        } else {
          val = *(const short8*)&in1b[base1 + (size_t)px*(CIN-SPLIT) + cb - SPLIT];
        }
        *(short8*)&lds[ky][px+1][cb] = val;
      }
    }
    for(int c8 = tid; c8 < 2*(CIN/8); c8 += 256){
      int which = c8 / (CIN/8); int cb = (c8 % (CIN/8))*8;
      *(short8*)&lds[ky][which ? (WW+1) : 0][cb] = Z8;
    }
  }
  __syncthreads();

  const f32x4 zf = {0.f,0.f,0.f,0.f};
  f32x4 acc[3][NTW];
  #pragma unroll
  for(int mt=0; mt<3; mt++)
    #pragma unroll
    for(int i=0; i<NTW; i++) acc[mt][i] = zf;

  #pragma unroll
  for(int ky=0; ky<3; ky++)
  #pragma unroll
  for(int kx=0; kx<3; kx++)
  #pragma unroll
  for(int ks=0; ks<CIN/32; ks++){
    short8 a[3];
    #pragma unroll
    for(int mt=0; mt<3; mt++)
      a[mt] = *(const short8*)&lds[ky][mt*16 + col + kx][ks*32 + g*8];
    #pragma unroll
    for(int i=0; i<NTW; i++){
      int co0 = (wave + 4*i)*16;
      const u16* wp = Wt + ((size_t)((ky*3+kx)*COUT) + co0 + col)*CIN + ks*32 + g*8;
      short8 bfr = *(const short8*)wp;
      #pragma unroll
      for(int mt=0; mt<3; mt++)
        acc[mt][i] = mfma16(a[mt], bfr, acc[mt][i]);
    }
  }

  if constexpr (!GATE){
    u16* out0 = (u16*)out0v;
    #pragma unroll
    for(int i=0; i<NTW; i++){
      int co = (wave + 4*i)*16 + col;
      float bs = bias[co];
      u16* op = out0 + (size_t)(b*HH + y)*WW*COUT + co;
      #pragma unroll
      for(int mt=0; mt<3; mt++)
        #pragma unroll
        for(int r=0; r<4; r++){
          int px = mt*16 + g*4 + r;
          op[(size_t)px*COUT] = f2bf(acc[mt][i][r] + bs);
        }
    }
  } else {
    float* oh = (float*)out0v;
    float* om = (float*)out1v;
    int c = wave*16 + col;
    float bo = bias[c], bg = bias[64+c], bgi = bias[128+c];
    #pragma unroll
    for(int mt=0; mt<3; mt++)
      #pragma unroll
      for(int r=0; r<4; r++){
        int px = mt*16 + g*4 + r;
        size_t idx = ((size_t)(b*HH + y)*WW + px)*64 + c;
        float mo = acc[mt][0][r] + bo;
        float mg = acc[mt][1][r] + bg;
        float gi = acc[mt][2][r] + bgi;
        float mval = mem[idx];
        float si = 1.f/(1.f + __expf(-gi));
        float nm = (1.f - si)*mval + si*tanhf(mg);
        float nh = (1.f/(1.f + __expf(-mo)))*nm;
        oh[idx] = nh;
        om[idx] = nm;
      }
  }
}

// ---------------- launcher ----------------
extern "C" void kernel_launch(void* const* d_in, const int* in_sizes, int n_in,
                              void* d_out, int out_size, void* d_ws, size_t ws_size,
                              hipStream_t stream){
  (void)in_sizes; (void)n_in; (void)out_size; (void)ws_size;
  const float* h   = (const float*)d_in[0];
  const float* m   = (const float*)d_in[1];
  const float* Wq  = (const float*)d_in[2];  const float* bq  = (const float*)d_in[3];
  const float* Wk  = (const float*)d_in[4];  const float* bk  = (const float*)d_in[5];
  const float* Wk2 = (const float*)d_in[6];  const float* bk2 = (const float*)d_in[7];
  const float* Wv  = (const float*)d_in[8];  const float* bv  = (const float*)d_in[9];
  const float* Wv2 = (const float*)d_in[10]; const float* bv2 = (const float*)d_in[11];
  const float* Wz  = (const float*)d_in[12]; const float* bz  = (const float*)d_in[13];
  const float* Wm  = (const float*)d_in[14]; const float* bm  = (const float*)d_in[15];

  const size_t NPIX = (size_t)BB*NSEQ*DD;  // 1,179,648

  u16* ws = (u16*)d_ws;
  u16* WtQ  = ws + 0;            // all 7 transposed weights contiguous: 663552 u16
  u16* WtK  = ws + 36864;
  u16* WtK2 = ws + 73728;
  u16* WtV  = ws + 110592;
  u16* WtV2 = ws + 147456;
  u16* WtZ  = ws + 184320;
  u16* WtM  = ws + 331776;
  u16* slotA = ws + 663552;      // q;   later Z low half
  u16* slotB = slotA + NPIX;     // k_h; later Z high half
  u16* slotC = slotB + NPIX;     // v_h^T [b][d][seq]
  u16* slotD = slotC + NPIX;     // k_m
  u16* slotE = slotD + NPIX;     // v_m^T [b][d][seq]
  u16* pox   = slotE + NPIX;     // partial regions 4..5 (2 NPIX)
  float2* ml = (float2*)(pox + 2*NPIX);   // 6*BB*NSEQ float2 = 884 KB; total ws 18.7 MB
  u16* Zb    = slotA;            // 2*NPIX spanning A+B

  float* outh = (float*)d_out;   // final new_h (f32)
  float* outm = outh + NPIX;     // final new_m (f32)
  u16* po = (u16*)d_out;         // partial regions 0..3 (4 NPIX u16)
  u16* zh = po;                  // after combine: z_h
  u16* zm = po + NPIX;           // after combine: z_m

  WtSrcs wsrc;
  wsrc.src[0]=Wq; wsrc.src[1]=Wk; wsrc.src[2]=Wk2; wsrc.src[3]=Wv; wsrc.src[4]=Wv2;
  wsrc.src[5]=Wz; wsrc.src[6]=Wm;
  wtrans_all<<<dim3(2592), 256, 0, stream>>>(wsrc, ws);

  ConvPtrs ph;
  ph.W[0]=WtQ;  ph.W[1]=WtK;  ph.W[2]=WtV;
  ph.bias[0]=bq; ph.bias[1]=bk; ph.bias[2]=bv;
  ph.out[0]=slotA; ph.out[1]=slotB; ph.out[2]=slotC;
  ph.vt[0]=0; ph.vt[1]=0; ph.vt[2]=1;
  ph.nc = 3;

  ConvPtrs pm;
  pm.W[0]=WtK2; pm.W[1]=WtV2; pm.W[2]=WtV2;
  pm.bias[0]=bk2; pm.bias[1]=bv2; pm.bias[2]=bv2;
  pm.out[0]=slotD; pm.out[1]=slotE; pm.out[2]=slotE;
  pm.vt[0]=0; pm.vt[1]=1; pm.vt[2]=1;
  pm.nc = 2;

  // both conv64 streams in one dispatch (z: 0=h, 1=m)
  conv64_mfma<<<dim3(BB*HH, 1, 2), 256, 0, stream>>>(h, m, ph, pm);

  // stream-split + 3-way split-K attention -> partials (d_out + ws) + (m,l) in ws
  attn2_mfma<<<dim3(NSEQ/64, BB, 6), 256, 0, stream>>>(
      slotA, slotB, slotC, slotD, slotE, po, pox, ml);

  // combine chunk triples -> z_h, z_m (in d_out)
  attn_combine<<<dim3(2048), 256, 0, stream>>>(po, pox, ml);

  // Z = conv(concat(z_h, z_m)) -> bf16 into Zb (q, k_h slots dead)
  bigconv_mfma<128,128,64,false,false><<<dim3(BB*HH), 256, 0, stream>>>(
      zh, zm, (const float*)0, WtZ, bz, (void*)Zb, (void*)0, (const float*)0);

  // combined = conv(concat(Z, h)); fused gating -> f32 outputs
  bigconv_mfma<192,192,128,true,true><<<dim3(BB*HH), 256, 0, stream>>>(
      Zb, (const u16*)0, h, WtM, bm, (void*)outh, (void*)outm, m);
}